// Round 2
// baseline (57268.011 us; speedup 1.0000x reference)
//
#include <hip/hip_runtime.h>
#include <hip/hip_bf16.h>
#include <cstdint>

#define BATCH 8
#define LATC 256
#define NCODE 1024
#define NLVL 4

// ---- load/store helpers (fp32 compute, fp32-or-bf16 storage) ----
__device__ __forceinline__ float ldf(const float* p, long long i) { return p[i]; }
__device__ __forceinline__ float ldf(const __hip_bfloat16* p, long long i) {
  return __bfloat162float(p[i]);
}
__device__ __forceinline__ void st2(float* p, float a, float b) {
  *reinterpret_cast<float2*>(p) = make_float2(a, b);
}
__device__ __forceinline__ void st2(__hip_bfloat16* p, float a, float b) {
  __hip_bfloat162 v;
  v.x = __float2bfloat16(a);
  v.y = __float2bfloat16(b);
  *reinterpret_cast<__hip_bfloat162*>(p) = v;
}

// ---------------- encoder conv k4 s2 p1 (+relu), NCHW, OIHW ----------------
__global__ __launch_bounds__(256) void conv4s2(
    const float* __restrict__ in, const float* __restrict__ w,
    const float* __restrict__ bias, float* __restrict__ out,
    int Cin, int Cout, int Hin, int Win, int relu) {
  const int Hout = Hin >> 1, Wout = Win >> 1;
  const int cogn = Cout >> 2;
  long long total = (long long)BATCH * cogn * Hout * Wout;
  long long gid = (long long)blockIdx.x * blockDim.x + threadIdx.x;
  if (gid >= total) return;
  int wo = (int)(gid % Wout); long long t = gid / Wout;
  int ho = (int)(t % Hout); t /= Hout;
  int cog = (int)(t % cogn); int n = (int)(t / cogn);
  int co0 = cog << 2;
  float a0 = bias[co0], a1 = bias[co0 + 1], a2 = bias[co0 + 2], a3 = bias[co0 + 3];
  const int hi0 = 2 * ho - 1, wi0 = 2 * wo - 1;
  const long long wstride = (long long)Cin * 16;
  for (int ci = 0; ci < Cin; ++ci) {
    const float* __restrict__ ip = in + ((long long)(n * Cin + ci) * Hin) * Win;
    const float* __restrict__ wp = w + (long long)co0 * wstride + (long long)ci * 16;
#pragma unroll
    for (int kh = 0; kh < 4; ++kh) {
      int hi = hi0 + kh;
      if ((unsigned)hi >= (unsigned)Hin) continue;
#pragma unroll
      for (int kw = 0; kw < 4; ++kw) {
        int wi = wi0 + kw;
        if ((unsigned)wi >= (unsigned)Win) continue;
        float v = ip[(long long)hi * Win + wi];
        int k = (kh << 2) + kw;
        a0 = fmaf(v, wp[k], a0);
        a1 = fmaf(v, wp[wstride + k], a1);
        a2 = fmaf(v, wp[2 * wstride + k], a2);
        a3 = fmaf(v, wp[3 * wstride + k], a3);
      }
    }
  }
  if (relu) {
    a0 = fmaxf(a0, 0.f); a1 = fmaxf(a1, 0.f);
    a2 = fmaxf(a2, 0.f); a3 = fmaxf(a3, 0.f);
  }
  long long cs = (long long)Hout * Wout;
  long long ob = ((long long)(n * Cout + co0) * Hout + ho) * Wout + wo;
  out[ob] = a0; out[ob + cs] = a1; out[ob + 2 * cs] = a2; out[ob + 3 * cs] = a3;
}

// ---------------- 1x1 conv (projection), no relu ----------------
__global__ __launch_bounds__(256) void conv1x1(
    const float* __restrict__ in, const float* __restrict__ w,
    const float* __restrict__ bias, float* __restrict__ out, int Cin, int Cout) {
  const int HW = 1024;
  const int cogn = Cout >> 2;
  long long total = (long long)BATCH * cogn * HW;
  long long gid = (long long)blockIdx.x * blockDim.x + threadIdx.x;
  if (gid >= total) return;
  int hw = (int)(gid % HW); long long t = gid / HW;
  int cog = (int)(t % cogn); int n = (int)(t / cogn);
  int co0 = cog << 2;
  float a0 = bias[co0], a1 = bias[co0 + 1], a2 = bias[co0 + 2], a3 = bias[co0 + 3];
  for (int ci = 0; ci < Cin; ++ci) {
    float v = in[((long long)(n * Cin + ci)) * HW + hw];
    const float* __restrict__ wp = w + (long long)co0 * Cin + ci;
    a0 = fmaf(v, wp[0], a0);
    a1 = fmaf(v, wp[Cin], a1);
    a2 = fmaf(v, wp[2 * Cin], a2);
    a3 = fmaf(v, wp[3 * Cin], a3);
  }
  long long ob = ((long long)(n * Cout + co0)) * HW + hw;
  out[ob] = a0; out[ob + HW] = a1; out[ob + 2 * HW] = a2; out[ob + 3 * HW] = a3;
}

// ---------------- per-code squared norms of the codebooks ----------------
__global__ __launch_bounds__(256) void emb_norms(
    const float* __restrict__ emb, float* __restrict__ en) {
  int k = blockIdx.x * blockDim.x + threadIdx.x;
  if (k >= NLVL * NCODE) return;
  const float* __restrict__ e = emb + (long long)k * LATC;
  float s = 0.f;
  for (int c = 0; c < LATC; ++c) s = fmaf(e[c], e[c], s);
  en[k] = s;
}

// ---------------- residual quantization: one block per pixel, all 4 levels ----------------
__global__ __launch_bounds__(256) void rq_kernel(
    const float* __restrict__ z, const float* __restrict__ emb,
    const float* __restrict__ en, float* __restrict__ zq_out,
    float* __restrict__ resid_out, float* __restrict__ codes_out) {
  const int p = blockIdx.x;            // 0..8191  = n*1024 + hw
  const int n = p >> 10, hw = p & 1023;
  const int t = threadIdx.x;           // channel this thread owns
  __shared__ float r_sh[LATC];
  __shared__ float red_d[256];
  __shared__ int red_i[256];
  const long long zbase = ((long long)n * LATC) * 1024 + hw;
  const float zc = z[zbase + (long long)t * 1024];
  float rc = zc, zqacc = 0.f;
  for (int l = 0; l < NLVL; ++l) {
    resid_out[(((long long)(l * BATCH + n)) * LATC + t) * 1024 + hw] = rc;
    r_sh[t] = rc;
    red_d[t] = rc * rc;
    __syncthreads();
    for (int s = 128; s > 0; s >>= 1) {
      if (t < s) red_d[t] += red_d[t + s];
      __syncthreads();
    }
    const float sumr2 = red_d[0];
    __syncthreads();
    const float* __restrict__ E = emb + (long long)l * NCODE * LATC;
    const float* __restrict__ enl = en + l * NCODE;
    float best = 3.4e38f; int bi = 0;
    for (int kk = 0; kk < 4; ++kk) {
      int k = (kk << 8) + t;
      const float* __restrict__ ek = E + (long long)k * LATC;
      float dot = 0.f;
      for (int c = 0; c < LATC; ++c) dot = fmaf(r_sh[c], ek[c], dot);
      float d2 = (sumr2 - 2.f * dot) + enl[k];
      if (d2 < best) { best = d2; bi = k; }   // k ascending per thread -> first-min kept
    }
    red_d[t] = best; red_i[t] = bi;
    __syncthreads();
    for (int s = 128; s > 0; s >>= 1) {
      if (t < s) {
        float od = red_d[t + s]; int oi = red_i[t + s];
        if (od < red_d[t] || (od == red_d[t] && oi < red_i[t])) {
          red_d[t] = od; red_i[t] = oi;
        }
      }
      __syncthreads();
    }
    const int idx = red_i[0];
    if (t == 0) codes_out[(long long)(l * BATCH + n) * 1024 + hw] = (float)idx;
    const float ec = E[(long long)idx * LATC + t];
    zqacc += ec;
    rc -= ec;
    __syncthreads();   // protect r_sh/red_* before next level rewrites them
  }
  zq_out[zbase + (long long)t * 1024] = zqacc;
}

// ---------------- transposed conv k4 s2 SAME (+relu), NCHW in/out, HWIO weights ----------------
// y[2i]   = w0*x[i-1] + w2*x[i];  y[2i+1] = w1*x[i] + w3*x[i+1]   (per axis)
template <typename TI, typename TO>
__global__ __launch_bounds__(256) void convT4s2_relu(
    const TI* __restrict__ in, const float* __restrict__ w,
    const float* __restrict__ bias, TO* __restrict__ out,
    int Cin, int Cout, int Hi, int Wi) {
  const int Ho = Hi << 1, Wo = Wi << 1;
  long long total = (long long)BATCH * Cout * Hi * Wi;
  long long gid = (long long)blockIdx.x * blockDim.x + threadIdx.x;
  if (gid >= total) return;
  int j = (int)(gid % Wi); long long t = gid / Wi;
  int i = (int)(t % Hi); t /= Hi;
  int co = (int)(t % Cout); int n = (int)(t / Cout);
  const float b = bias[co];
  float a00 = b, a01 = b, a10 = b, a11 = b;
  const long long tapstride = (long long)Cin * Cout;
  const float* __restrict__ wbase = w + co;
  for (int ci = 0; ci < Cin; ++ci) {
    const TI* __restrict__ ip = in + ((long long)(n * Cin + ci) * Hi) * Wi;
    float xv[3][3];
#pragma unroll
    for (int dy = 0; dy < 3; ++dy) {
      int y = i - 1 + dy;
      bool yok = (unsigned)y < (unsigned)Hi;
#pragma unroll
      for (int dx = 0; dx < 3; ++dx) {
        int xx = j - 1 + dx;
        xv[dy][dx] = (yok && (unsigned)xx < (unsigned)Wi) ? ldf(ip, (long long)y * Wi + xx) : 0.f;
      }
    }
    const float* __restrict__ wp = wbase + (long long)ci * Cout;
#define WT(kh, kw) wp[((kh) * 4 + (kw)) * tapstride]
    a00 = fmaf(xv[0][0], WT(0, 0), a00); a00 = fmaf(xv[0][1], WT(0, 2), a00);
    a00 = fmaf(xv[1][0], WT(2, 0), a00); a00 = fmaf(xv[1][1], WT(2, 2), a00);
    a01 = fmaf(xv[0][1], WT(0, 1), a01); a01 = fmaf(xv[0][2], WT(0, 3), a01);
    a01 = fmaf(xv[1][1], WT(2, 1), a01); a01 = fmaf(xv[1][2], WT(2, 3), a01);
    a10 = fmaf(xv[1][0], WT(1, 0), a10); a10 = fmaf(xv[1][1], WT(1, 2), a10);
    a10 = fmaf(xv[2][0], WT(3, 0), a10); a10 = fmaf(xv[2][1], WT(3, 2), a10);
    a11 = fmaf(xv[1][1], WT(1, 1), a11); a11 = fmaf(xv[1][2], WT(1, 3), a11);
    a11 = fmaf(xv[2][1], WT(3, 1), a11); a11 = fmaf(xv[2][2], WT(3, 3), a11);
#undef WT
  }
  a00 = fmaxf(a00, 0.f); a01 = fmaxf(a01, 0.f);
  a10 = fmaxf(a10, 0.f); a11 = fmaxf(a11, 0.f);
  long long ob = ((long long)(n * Cout + co) * Ho + 2 * i) * Wo + 2 * j;
  st2(out + ob, a00, a01);
  st2(out + ob + Wo, a10, a11);
}

// ---------------- final 3x3 conv s1 p1, no relu (bf16 in, f32 out) ----------------
__global__ __launch_bounds__(256) void conv3x3_out(
    const __hip_bfloat16* __restrict__ in, const float* __restrict__ w,
    const float* __restrict__ bias, float* __restrict__ out) {
  const int Cin = 128, H = 256, W = 256, Cout = 3;
  long long total = (long long)BATCH * Cout * H * W;
  long long gid = (long long)blockIdx.x * blockDim.x + threadIdx.x;
  if (gid >= total) return;
  int x = (int)(gid % W); long long t = gid / W;
  int y = (int)(t % H); t /= H;
  int co = (int)(t % Cout); int n = (int)(t / Cout);
  float acc = bias[co];
  for (int ci = 0; ci < Cin; ++ci) {
    const __hip_bfloat16* __restrict__ ip = in + ((long long)(n * Cin + ci) * H) * W;
    const float* __restrict__ wp = w + ((long long)(co * Cin + ci)) * 9;
#pragma unroll
    for (int kh = 0; kh < 3; ++kh) {
      int yy = y + kh - 1;
      if ((unsigned)yy >= (unsigned)H) continue;
#pragma unroll
      for (int kw = 0; kw < 3; ++kw) {
        int xx = x + kw - 1;
        if ((unsigned)xx >= (unsigned)W) continue;
        acc = fmaf(__bfloat162float(ip[(long long)yy * W + xx]), wp[kh * 3 + kw], acc);
      }
    }
  }
  out[gid] = acc;
}

extern "C" void kernel_launch(void* const* d_in, const int* in_sizes, int n_in,
                              void* d_out, int out_size, void* d_ws, size_t ws_size,
                              hipStream_t stream) {
  const float* x   = (const float*)d_in[0];
  const float* ew0 = (const float*)d_in[1];  const float* eb0 = (const float*)d_in[2];
  const float* ew1 = (const float*)d_in[3];  const float* eb1 = (const float*)d_in[4];
  const float* ew2 = (const float*)d_in[5];  const float* eb2 = (const float*)d_in[6];
  const float* pw  = (const float*)d_in[7];  const float* pb  = (const float*)d_in[8];
  const float* dw0 = (const float*)d_in[9];  const float* db0 = (const float*)d_in[10];
  const float* dw1 = (const float*)d_in[11]; const float* db1 = (const float*)d_in[12];
  const float* dw2 = (const float*)d_in[13]; const float* db2 = (const float*)d_in[14];
  const float* ow  = (const float*)d_in[15]; const float* ob  = (const float*)d_in[16];
  const float* emb = (const float*)d_in[17];

  float* out   = (float*)d_out;
  float* recon = out;                 // [8,3,256,256]   1,572,864
  float* z     = out + 1572864;       // [8,256,32,32]   2,097,152
  float* zq    = out + 3670016;       // [8,256,32,32]   2,097,152
  float* resid = out + 5767168;       // [4,8,256,32,32] 8,388,608
  float* codes = out + 14155776;      // [4,8,32,32]     32,768 (as float)

  // workspace layout — peak usage ~201.4 MB:
  //   en   @ 0          (16 KiB, reserve 64 KiB)
  //   A    @ 64 KiB     encoder: e0 (67.1 MB) then e2 (16.8 MB);  decoder: dd1 (bf16, 67.1 MB)
  //   B    @ 64K+67.1M  encoder: e1 (33.6 MB);                    decoder: dd0 (bf16, 33.6 MB),
  //                     then dd2 (bf16, 134.2 MB, overlays dead dd0)
  char* ws = (char*)d_ws;
  const size_t OFF_A = 65536ULL;
  const size_t OFF_B = 65536ULL + 67108864ULL;     // 67,174,400
  float* en = (float*)(ws);
  float* e0 = (float*)(ws + OFF_A);                // [8,128,128,128] f32
  float* e1 = (float*)(ws + OFF_B);                // [8,256,64,64]   f32
  float* e2 = (float*)(ws + OFF_A);                // [8,512,32,32]   f32
  __hip_bfloat16* dd0 = (__hip_bfloat16*)(ws + OFF_B);  // [8,512,64,64]
  __hip_bfloat16* dd1 = (__hip_bfloat16*)(ws + OFF_A);  // [8,256,128,128]
  __hip_bfloat16* dd2 = (__hip_bfloat16*)(ws + OFF_B);  // [8,128,256,256]

  dim3 blk(256);
  auto g = [](long long tot) { return dim3((unsigned)((tot + 255) / 256)); };

  // encoder (all fp32 — codes need near-exact argmin downstream)
  conv4s2<<<g(8LL * 32 * 128 * 128), blk, 0, stream>>>(x, ew0, eb0, e0, 3, 128, 256, 256, 1);
  conv4s2<<<g(8LL * 64 * 64 * 64), blk, 0, stream>>>(e0, ew1, eb1, e1, 128, 256, 128, 128, 1);
  conv4s2<<<g(8LL * 128 * 32 * 32), blk, 0, stream>>>(e1, ew2, eb2, e2, 256, 512, 64, 64, 1);
  conv1x1<<<g(8LL * 64 * 1024), blk, 0, stream>>>(e2, pw, pb, z, 512, 256);

  // residual quantization (z_q_st == z_q in value; decoder reads zq directly)
  emb_norms<<<g(4096), blk, 0, stream>>>(emb, en);
  rq_kernel<<<dim3(8192), blk, 0, stream>>>(z, emb, en, zq, resid, codes);

  // decoder (bf16 activation storage, fp32 compute)
  convT4s2_relu<float, __hip_bfloat16>
      <<<g(8LL * 512 * 32 * 32), blk, 0, stream>>>(zq, dw0, db0, dd0, 256, 512, 32, 32);
  convT4s2_relu<__hip_bfloat16, __hip_bfloat16>
      <<<g(8LL * 256 * 64 * 64), blk, 0, stream>>>(dd0, dw1, db1, dd1, 512, 256, 64, 64);
  convT4s2_relu<__hip_bfloat16, __hip_bfloat16>
      <<<g(8LL * 128 * 128 * 128), blk, 0, stream>>>(dd1, dw2, db2, dd2, 256, 128, 128, 128);
  conv3x3_out<<<g(8LL * 3 * 256 * 256), blk, 0, stream>>>(dd2, ow, ob, recon);
}

// Round 3
// 7125.485 us; speedup vs baseline: 8.0371x; 8.0371x over previous
//
#include <hip/hip_runtime.h>
#include <hip/hip_bf16.h>
#include <cstdint>

#define BATCH 8
#define LATC 256
#define NCODE 1024
#define NLVL 4

typedef __attribute__((ext_vector_type(8))) short bf16x8v;
typedef __attribute__((ext_vector_type(4))) float f32x4v;

__device__ __forceinline__ unsigned short f2b(float f) {
  __hip_bfloat16 h = __float2bfloat16(f);
  return *reinterpret_cast<unsigned short*>(&h);
}

// async global->LDS 16B: LDS base = readfirstlane(lane0 offset), HW writes base + lane*16
__device__ __forceinline__ void gl_lds16(const void* gptr, unsigned lds_byte_off) {
  unsigned m0v = __builtin_amdgcn_readfirstlane(lds_byte_off);
  asm volatile("s_mov_b32 m0, %0\n"
               "global_load_lds_dwordx4 %1, off\n" ::"s"(m0v), "v"(gptr)
               : "memory");
}

// ---------------- encoder conv k4 s2 p1 (+relu), 4 couts x 2x2 pixels per thread ----------------
__global__ __launch_bounds__(256) void conv4s2_v2(
    const float* __restrict__ in, const float* __restrict__ w,
    const float* __restrict__ bias, float* __restrict__ out,
    int Cin, int Cout, int Hin, int Win, int relu) {
  const int Hout = Hin >> 1, Wout = Win >> 1;
  const int H2 = Hout >> 1, W2 = Wout >> 1;
  const int cogn = Cout >> 2;
  long long total = (long long)BATCH * cogn * H2 * W2;
  long long gid = (long long)blockIdx.x * blockDim.x + threadIdx.x;
  if (gid >= total) return;
  int w2 = (int)(gid % W2); long long t = gid / W2;
  int h2 = (int)(t % H2); t /= H2;
  int cog = (int)(t % cogn); int n = (int)(t / cogn);
  int co0 = cog << 2;
  float a[4][2][2];
#pragma unroll
  for (int j = 0; j < 4; ++j) {
    float b = bias[co0 + j];
    a[j][0][0] = b; a[j][0][1] = b; a[j][1][0] = b; a[j][1][1] = b;
  }
  const int hi0 = 4 * h2 - 1, wi0 = 4 * w2 - 1;
  const long long wstride = (long long)Cin * 16;
  for (int ci = 0; ci < Cin; ++ci) {
    const float* __restrict__ ip = in + ((long long)(n * Cin + ci) * Hin) * Win;
    float xv[6][6];
#pragma unroll
    for (int r = 0; r < 6; ++r) {
      int hi = hi0 + r;
      bool ok = (unsigned)hi < (unsigned)Hin;
#pragma unroll
      for (int c = 0; c < 6; ++c) {
        int wi = wi0 + c;
        xv[r][c] = (ok && (unsigned)wi < (unsigned)Win) ? ip[(long long)hi * Win + wi] : 0.f;
      }
    }
    const float* __restrict__ wp = w + (long long)co0 * wstride + (long long)ci * 16;
#pragma unroll
    for (int kh = 0; kh < 4; ++kh) {
#pragma unroll
      for (int kw = 0; kw < 4; ++kw) {
        int k = (kh << 2) + kw;
        float w0 = wp[k], w1 = wp[wstride + k], w2v = wp[2 * wstride + k], w3 = wp[3 * wstride + k];
#pragma unroll
        for (int dy = 0; dy < 2; ++dy)
#pragma unroll
          for (int dx = 0; dx < 2; ++dx) {
            float v = xv[2 * dy + kh][2 * dx + kw];
            a[0][dy][dx] = fmaf(v, w0, a[0][dy][dx]);
            a[1][dy][dx] = fmaf(v, w1, a[1][dy][dx]);
            a[2][dy][dx] = fmaf(v, w2v, a[2][dy][dx]);
            a[3][dy][dx] = fmaf(v, w3, a[3][dy][dx]);
          }
      }
    }
  }
  long long cs = (long long)Hout * Wout;
  long long ob0 = ((long long)(n * Cout + co0) * Hout + 2 * h2) * Wout + 2 * w2;
#pragma unroll
  for (int j = 0; j < 4; ++j)
#pragma unroll
    for (int dy = 0; dy < 2; ++dy)
#pragma unroll
      for (int dx = 0; dx < 2; ++dx) {
        float v = a[j][dy][dx];
        if (relu) v = fmaxf(v, 0.f);
        out[ob0 + j * cs + (long long)dy * Wout + dx] = v;
      }
}

// ---------------- 1x1 conv (projection), no relu ----------------
__global__ __launch_bounds__(256) void conv1x1(
    const float* __restrict__ in, const float* __restrict__ w,
    const float* __restrict__ bias, float* __restrict__ out, int Cin, int Cout) {
  const int HW = 1024;
  const int cogn = Cout >> 2;
  long long total = (long long)BATCH * cogn * HW;
  long long gid = (long long)blockIdx.x * blockDim.x + threadIdx.x;
  if (gid >= total) return;
  int hw = (int)(gid % HW); long long t = gid / HW;
  int cog = (int)(t % cogn); int n = (int)(t / cogn);
  int co0 = cog << 2;
  float a0 = bias[co0], a1 = bias[co0 + 1], a2 = bias[co0 + 2], a3 = bias[co0 + 3];
  for (int ci = 0; ci < Cin; ++ci) {
    float v = in[((long long)(n * Cin + ci)) * HW + hw];
    const float* __restrict__ wp = w + (long long)co0 * Cin + ci;
    a0 = fmaf(v, wp[0], a0);
    a1 = fmaf(v, wp[Cin], a1);
    a2 = fmaf(v, wp[2 * Cin], a2);
    a3 = fmaf(v, wp[3 * Cin], a3);
  }
  long long ob = ((long long)(n * Cout + co0)) * HW + hw;
  out[ob] = a0; out[ob + HW] = a1; out[ob + 2 * HW] = a2; out[ob + 3 * HW] = a3;
}

// ---------------- per-code squared norms ----------------
__global__ __launch_bounds__(256) void emb_norms(
    const float* __restrict__ emb, float* __restrict__ en) {
  int k = blockIdx.x * blockDim.x + threadIdx.x;
  if (k >= NLVL * NCODE) return;
  const float* __restrict__ e = emb + (long long)k * LATC;
  float s = 0.f;
  for (int c = 0; c < LATC; ++c) s = fmaf(e[c], e[c], s);
  en[k] = s;
}

// ---------------- residual quantization v2: 32 pixels/block, LDS-tiled codebook ----------------
#define RQ_P 32
#define RQ_CT 32
#define RQ_RS 260  // floats per LDS row (65 float4s, 16B-aligned)

__global__ __launch_bounds__(256) void rq_kernel2(
    const float* __restrict__ z, const float* __restrict__ emb,
    const float* __restrict__ en, float* __restrict__ zq_out,
    float* __restrict__ resid_out, float* __restrict__ codes_out) {
  __shared__ float e_sh[RQ_CT * RQ_RS];
  __shared__ float r_sh[RQ_P * RQ_RS];
  __shared__ float sum_sh[RQ_P];
  __shared__ int code_sh[RQ_P];
  const int tid = threadIdx.x;
  const int blk = blockIdx.x;  // 0..255
  const int n = (blk * RQ_P) >> 10;
  const int hw0 = (blk * RQ_P) & 1023;
  const long long zb = ((long long)n * LATC) * 1024 + hw0;

  // init: z -> r_sh, write resid level 0 (coalesced)
  for (int it = 0; it < 32; ++it) {
    int u = it * 256 + tid;
    int c = u >> 5, pix = u & 31;
    float v = z[zb + (long long)c * 1024 + pix];
    r_sh[pix * RQ_RS + c] = v;
    resid_out[((long long)n * LATC + c) * 1024 + hw0 + pix] = v;
  }
  __syncthreads();

  const int code_l = tid & 31;
  const int pixoff = tid >> 5;  // 0..7
  const int upix = tid >> 3;    // 0..31
  const int ucg = tid & 7;

  for (int l = 0; l < NLVL; ++l) {
    // per-pixel sum(r^2)
    {
      float s = 0.f;
#pragma unroll
      for (int it = 0; it < 8; ++it) {
        int c4 = ucg + it * 8;
        float4 r4 = *(const float4*)&r_sh[upix * RQ_RS + c4 * 4];
        s += r4.x * r4.x + r4.y * r4.y + r4.z * r4.z + r4.w * r4.w;
      }
      s += __shfl_xor(s, 1); s += __shfl_xor(s, 2); s += __shfl_xor(s, 4);
      if (ucg == 0) sum_sh[upix] = s;
    }
    __syncthreads();
    const float* __restrict__ E = emb + (long long)l * NCODE * LATC;
    const float* __restrict__ enl = en + l * NCODE;
    float best[4]; int bidx[4];
#pragma unroll
    for (int g = 0; g < 4; ++g) { best[g] = 3.4e38f; bidx[g] = 0; }
    for (int tile = 0; tile < NCODE / RQ_CT; ++tile) {
      const float* __restrict__ Et = E + (long long)tile * RQ_CT * LATC;
      for (int it = 0; it < 32; ++it) {
        int u = it * 256 + tid;
        int cc = u >> 8, ch = u & 255;
        e_sh[cc * RQ_RS + ch] = Et[cc * LATC + ch];
      }
      __syncthreads();
      float acc[4] = {0.f, 0.f, 0.f, 0.f};
      for (int c4 = 0; c4 < 64; ++c4) {
        float4 e4 = *(const float4*)&e_sh[code_l * RQ_RS + c4 * 4];
#pragma unroll
        for (int g = 0; g < 4; ++g) {
          float4 r4 = *(const float4*)&r_sh[(g * 8 + pixoff) * RQ_RS + c4 * 4];
          acc[g] = fmaf(r4.x, e4.x, acc[g]);
          acc[g] = fmaf(r4.y, e4.y, acc[g]);
          acc[g] = fmaf(r4.z, e4.z, acc[g]);
          acc[g] = fmaf(r4.w, e4.w, acc[g]);
        }
      }
      int code = tile * RQ_CT + code_l;
      float ek2 = enl[code];
#pragma unroll
      for (int g = 0; g < 4; ++g) {
        float d2 = (sum_sh[g * 8 + pixoff] - 2.f * acc[g]) + ek2;
        if (d2 < best[g]) { best[g] = d2; bidx[g] = code; }
      }
      __syncthreads();
    }
    // argmin across 32 code-lanes (tie -> lower index)
#pragma unroll
    for (int g = 0; g < 4; ++g) {
      float bd = best[g]; int bi = bidx[g];
#pragma unroll
      for (int m = 1; m < 32; m <<= 1) {
        float od = __shfl_xor(bd, m);
        int oi = __shfl_xor(bi, m);
        if (od < bd || (od == bd && oi < bi)) { bd = od; bi = oi; }
      }
      if (code_l == 0) {
        int pix = g * 8 + pixoff;
        code_sh[pix] = bi;
        codes_out[(long long)(l * BATCH + n) * 1024 + hw0 + pix] = (float)bi;
      }
    }
    __syncthreads();
    // update r -= E[sel]; write next-level residual
    {
      int sel = code_sh[upix];
      const float* __restrict__ esel = E + (long long)sel * LATC;
#pragma unroll
      for (int it = 0; it < 8; ++it) {
        int c4 = ucg + it * 8;
        float4 r4 = *(const float4*)&r_sh[upix * RQ_RS + c4 * 4];
        float4 e4 = *(const float4*)&esel[c4 * 4];
        r4.x -= e4.x; r4.y -= e4.y; r4.z -= e4.z; r4.w -= e4.w;
        *(float4*)&r_sh[upix * RQ_RS + c4 * 4] = r4;
        if (l < NLVL - 1) {
          long long rb = ((long long)((l + 1) * BATCH + n) * LATC + c4 * 4) * 1024 + hw0 + upix;
          resid_out[rb] = r4.x;
          resid_out[rb + 1024] = r4.y;
          resid_out[rb + 2048] = r4.z;
          resid_out[rb + 3072] = r4.w;
        }
      }
    }
    __syncthreads();
  }
  // zq = z - r_final
  for (int it = 0; it < 32; ++it) {
    int u = it * 256 + tid;
    int c = u >> 5, pix = u & 31;
    float zv = z[zb + (long long)c * 1024 + pix];
    zq_out[zb + (long long)c * 1024 + pix] = zv - r_sh[pix * RQ_RS + c];
  }
}

// ---------------- zq (NCHW f32) -> padded NHWC bf16 [8][34][34][256] ----------------
__global__ __launch_bounds__(256) void to_nhwc_s1(const float* __restrict__ zq,
                                                  unsigned short* __restrict__ o) {
  __shared__ float tsh[32][33];
  int bx = blockIdx.x;
  int ct = bx & 7, y = (bx >> 3) & 31, n = bx >> 8;
  int tid = threadIdx.x;
  int x = tid & 31, cl = tid >> 5;
#pragma unroll
  for (int it = 0; it < 4; ++it) {
    int ci = it * 8 + cl;
    tsh[ci][x] = zq[((long long)(n * 256 + ct * 32 + ci) * 32 + y) * 32 + x];
  }
  __syncthreads();
  int ci = tid & 31, xg = tid >> 5;
#pragma unroll
  for (int it = 0; it < 4; ++it) {
    int xw = it * 8 + xg;
    o[(((long long)n * 34 + y + 1) * 34 + xw + 1) * 256 + ct * 32 + ci] = f2b(tsh[ci][xw]);
  }
}

// ---------------- weight prep: HWIO f32 -> [4ph][CIN/32][4tap][COUT][32] bf16 ----------------
__global__ __launch_bounds__(256) void wprep_k(const float* __restrict__ w,
                                               unsigned short* __restrict__ o,
                                               int CINc, int COUTc) {
  long long total = 16LL * CINc * COUTc;
  long long gid = (long long)blockIdx.x * 256 + threadIdx.x;
  if (gid >= total) return;
  int ci32 = (int)(gid & 31); long long t = gid >> 5;
  int co = (int)(t % COUTc); t /= COUTc;
  int tap = (int)(t & 3); t >>= 2;
  int nch = CINc / 32;
  int ch = (int)(t % nch); int phase = (int)(t / nch);
  int py = phase >> 1, px = phase & 1;
  int ky = py + 2 * (tap >> 1), kx = px + 2 * (tap & 1);
  int ci = ch * 32 + ci32;
  float v = w[(((long long)ky * 4 + kx) * CINc + ci) * COUTc + co];
  o[gid] = f2b(v);
}

// ---------------- transposed conv k4 s2 via MFMA implicit GEMM ----------------
// in: padded NHWC bf16 [8][Hi+2][Wi+2][CIN]; out: NHWC-padded [8][2Hi+2][2Wi+2][COUT] (+relu)
// or NCHW bf16 [8][COUT][2Hi][2Wi] (+relu)
template <int CIN, int COUT, int TH, int TW, int Hi, int Wi, int NW, bool OUT_NCHW>
__global__ __launch_bounds__(NW * 64) void convt_mfma(
    const unsigned short* __restrict__ xin, const unsigned short* __restrict__ wprep,
    const float* __restrict__ bias, unsigned short* __restrict__ outp) {
  constexpr int TWP = TW + 2;
  constexpr int Hp = Hi + 2, Wp = Wi + 2;
  constexpr int NCH = CIN / 32;
  constexpr int TPB = NW * 64;
  constexpr int XU = (TH + 2) * TWP * 4;             // 16B units per chunk
  constexpr int XUP = ((XU + TPB - 1) / TPB) * TPB;  // padded units
  __shared__ unsigned short xlds[2][XUP * 8];
  __shared__ unsigned short wlds[2][4 * 128 * 32];

  const int tid = threadIdx.x;
  const int w = tid >> 6, lane = tid & 63;
  const int l15 = lane & 15, seg = lane >> 4;

  constexpr int SW = Wi / TW, SH = Hi / TH;
  int bx = blockIdx.x;
  int n = bx / (SH * SW); int srem = bx % (SH * SW);
  int i0 = (srem / SW) * TH, j0 = (srem % SW) * TW;
  int cob0 = blockIdx.y * 128;
  int phase = blockIdx.z; int py = phase >> 1, px = phase & 1;

  int wpix, wco;
  if (NW == 8) { wpix = w & 3; wco = w >> 2; }
  else { wpix = w & 1; wco = w >> 1; }

  const unsigned short* xsrc = xin + (long long)n * Hp * Wp * CIN;

  f32x4v acc[4][4];
  if (!OUT_NCHW) {
#pragma unroll
    for (int b = 0; b < 4; ++b) {
      float bv = bias[cob0 + (wco * 4 + b) * 16 + l15];
      f32x4v v = {bv, bv, bv, bv};
#pragma unroll
      for (int a = 0; a < 4; ++a) acc[a][b] = v;
    }
  } else {
#pragma unroll
    for (int a = 0; a < 4; ++a) {
      f32x4v v;
#pragma unroll
      for (int q = 0; q < 4; ++q) v[q] = bias[cob0 + (wco * 4 + a) * 16 + seg * 4 + q];
#pragma unroll
      for (int b = 0; b < 4; ++b) acc[a][b] = v;
    }
  }

  auto stageX = [&](int buf, int ch) {
#pragma unroll
    for (int it = 0; it < XUP / TPB; ++it) {
      int u = it * TPB + tid;
      int us = u < XU ? u : XU - 1;
      int row = us / (TWP * 4);
      int rem = us - row * (TWP * 4);
      int col = rem >> 2, sg = rem & 3;
      const unsigned short* g =
          xsrc + (((long long)(i0 + row) * Wp) + (j0 + col)) * CIN + ch * 32 + sg * 8;
      gl_lds16(g, (unsigned)(unsigned long long)(const void*)&xlds[buf][u * 8]);
    }
  };
  auto stageW = [&](int buf, int ch) {
    const unsigned short* wb = wprep + (((long long)phase * NCH + ch) * 4) * COUT * 32;
#pragma unroll
    for (int it = 0; it < 2048 / TPB; ++it) {
      int u = it * TPB + tid;
      int tap = u >> 9;
      int rem = u & 511;
      int co = rem >> 2, sg = rem & 3;
      gl_lds16(wb + ((long long)tap * COUT + cob0 + co) * 32 + sg * 8,
               (unsigned)(unsigned long long)(const void*)&wlds[buf][u * 8]);
    }
  };
  auto compute = [&](int buf) {
#pragma unroll
    for (int t = 0; t < 4; ++t) {
      int oy = (t >> 1) - 1 + py, ox = (t & 1) - 1 + px;
      bf16x8v xf[4], wf[4];
#pragma unroll
      for (int i = 0; i < 4; ++i) {
        int pl = (wpix * 4 + i) * 16 + l15;
        int r = pl / TW, c = pl % TW;
        int xrow = r + oy + 1, xcol = c + ox + 1;
        xf[i] = *(const bf16x8v*)&xlds[buf][(xrow * TWP + xcol) * 32 + seg * 8];
        int co = (wco * 4 + i) * 16 + l15;
        wf[i] = *(const bf16x8v*)&wlds[buf][(t * 128 + co) * 32 + seg * 8];
      }
#pragma unroll
      for (int a = 0; a < 4; ++a)
#pragma unroll
        for (int b = 0; b < 4; ++b) {
          if (OUT_NCHW)
            acc[a][b] = __builtin_amdgcn_mfma_f32_16x16x32_bf16(wf[a], xf[b], acc[a][b], 0, 0, 0);
          else
            acc[a][b] = __builtin_amdgcn_mfma_f32_16x16x32_bf16(xf[a], wf[b], acc[a][b], 0, 0, 0);
        }
    }
  };

  stageX(0, 0); stageW(0, 0);
  asm volatile("s_waitcnt vmcnt(0)" ::: "memory");
  __syncthreads();
  for (int ch = 0; ch < NCH; ++ch) {
    int cur = ch & 1;
    if (ch + 1 < NCH) { stageX(cur ^ 1, ch + 1); stageW(cur ^ 1, ch + 1); }
    compute(cur);
    asm volatile("s_waitcnt vmcnt(0)" ::: "memory");
    __syncthreads();
  }

  if (!OUT_NCHW) {
    constexpr int Wpo = 2 * Wi + 2;
    long long ob_n = (long long)n * (2 * Hi + 2) * Wpo * COUT;
#pragma unroll
    for (int a = 0; a < 4; ++a)
#pragma unroll
      for (int q = 0; q < 4; ++q) {
        int pl = (wpix * 4 + a) * 16 + seg * 4 + q;
        int r = pl / TW, c = pl % TW;
        int yo = 2 * (i0 + r) + py + 1, xo = 2 * (j0 + c) + px + 1;
        long long ob = ob_n + ((long long)yo * Wpo + xo) * COUT + cob0;
#pragma unroll
        for (int b = 0; b < 4; ++b) {
          float v = fmaxf(acc[a][b][q], 0.f);
          outp[ob + (wco * 4 + b) * 16 + l15] = f2b(v);
        }
      }
  } else {
    constexpr int Ho = 2 * Hi, Wo = 2 * Wi;
#pragma unroll
    for (int a = 0; a < 4; ++a)
#pragma unroll
      for (int q = 0; q < 4; ++q) {
        int co = cob0 + (wco * 4 + a) * 16 + seg * 4 + q;
#pragma unroll
        for (int b = 0; b < 4; ++b) {
          int pl = (wpix * 4 + b) * 16 + l15;
          int r = pl / TW, c = pl % TW;
          int yo = 2 * (i0 + r) + py, xo = 2 * (j0 + c) + px;
          float v = fmaxf(acc[a][b][q], 0.f);
          outp[((long long)(n * COUT + co) * Ho + yo) * Wo + xo] = f2b(v);
        }
      }
  }
}

// ---------------- final 3x3 conv s1 p1, bf16 NCHW in, f32 out ----------------
__global__ __launch_bounds__(256) void conv3x3_out(
    const __hip_bfloat16* __restrict__ in, const float* __restrict__ w,
    const float* __restrict__ bias, float* __restrict__ out) {
  const int Cin = 128, H = 256, W = 256, Cout = 3;
  long long total = (long long)BATCH * Cout * H * W;
  long long gid = (long long)blockIdx.x * blockDim.x + threadIdx.x;
  if (gid >= total) return;
  int x = (int)(gid % W); long long t = gid / W;
  int y = (int)(t % H); t /= H;
  int co = (int)(t % Cout); int n = (int)(t / Cout);
  float acc = bias[co];
  for (int ci = 0; ci < Cin; ++ci) {
    const __hip_bfloat16* __restrict__ ip = in + ((long long)(n * Cin + ci) * H) * W;
    const float* __restrict__ wp = w + ((long long)(co * Cin + ci)) * 9;
#pragma unroll
    for (int kh = 0; kh < 3; ++kh) {
      int yy = y + kh - 1;
      if ((unsigned)yy >= (unsigned)H) continue;
#pragma unroll
      for (int kw = 0; kw < 3; ++kw) {
        int xx = x + kw - 1;
        if ((unsigned)xx >= (unsigned)W) continue;
        acc = fmaf(__bfloat162float(ip[(long long)yy * W + xx]), wp[kh * 3 + kw], acc);
      }
    }
  }
  out[gid] = acc;
}

// ---------------- fallback scalar convT (round-2 path) ----------------
__device__ __forceinline__ float ldf(const float* p, long long i) { return p[i]; }
__device__ __forceinline__ float ldf(const __hip_bfloat16* p, long long i) {
  return __bfloat162float(p[i]);
}
__device__ __forceinline__ void st2(float* p, float a, float b) {
  *reinterpret_cast<float2*>(p) = make_float2(a, b);
}
__device__ __forceinline__ void st2(__hip_bfloat16* p, float a, float b) {
  __hip_bfloat162 v;
  v.x = __float2bfloat16(a); v.y = __float2bfloat16(b);
  *reinterpret_cast<__hip_bfloat162*>(p) = v;
}

template <typename TI, typename TO>
__global__ __launch_bounds__(256) void convT4s2_relu(
    const TI* __restrict__ in, const float* __restrict__ w,
    const float* __restrict__ bias, TO* __restrict__ out,
    int Cin, int Cout, int Hi, int Wi) {
  const int Ho = Hi << 1, Wo = Wi << 1;
  long long total = (long long)BATCH * Cout * Hi * Wi;
  long long gid = (long long)blockIdx.x * blockDim.x + threadIdx.x;
  if (gid >= total) return;
  int j = (int)(gid % Wi); long long t = gid / Wi;
  int i = (int)(t % Hi); t /= Hi;
  int co = (int)(t % Cout); int n = (int)(t / Cout);
  const float b = bias[co];
  float a00 = b, a01 = b, a10 = b, a11 = b;
  const long long tapstride = (long long)Cin * Cout;
  const float* __restrict__ wbase = w + co;
  for (int ci = 0; ci < Cin; ++ci) {
    const TI* __restrict__ ip = in + ((long long)(n * Cin + ci) * Hi) * Wi;
    float xv[3][3];
#pragma unroll
    for (int dy = 0; dy < 3; ++dy) {
      int y = i - 1 + dy;
      bool yok = (unsigned)y < (unsigned)Hi;
#pragma unroll
      for (int dx = 0; dx < 3; ++dx) {
        int xx = j - 1 + dx;
        xv[dy][dx] = (yok && (unsigned)xx < (unsigned)Wi) ? ldf(ip, (long long)y * Wi + xx) : 0.f;
      }
    }
    const float* __restrict__ wp = wbase + (long long)ci * Cout;
#define WT(kh, kw) wp[((kh) * 4 + (kw)) * tapstride]
    a00 = fmaf(xv[0][0], WT(0, 0), a00); a00 = fmaf(xv[0][1], WT(0, 2), a00);
    a00 = fmaf(xv[1][0], WT(2, 0), a00); a00 = fmaf(xv[1][1], WT(2, 2), a00);
    a01 = fmaf(xv[0][1], WT(0, 1), a01); a01 = fmaf(xv[0][2], WT(0, 3), a01);
    a01 = fmaf(xv[1][1], WT(2, 1), a01); a01 = fmaf(xv[1][2], WT(2, 3), a01);
    a10 = fmaf(xv[1][0], WT(1, 0), a10); a10 = fmaf(xv[1][1], WT(1, 2), a10);
    a10 = fmaf(xv[2][0], WT(3, 0), a10); a10 = fmaf(xv[2][1], WT(3, 2), a10);
    a11 = fmaf(xv[1][1], WT(1, 1), a11); a11 = fmaf(xv[1][2], WT(1, 3), a11);
    a11 = fmaf(xv[2][1], WT(3, 1), a11); a11 = fmaf(xv[2][2], WT(3, 3), a11);
#undef WT
  }
  a00 = fmaxf(a00, 0.f); a01 = fmaxf(a01, 0.f);
  a10 = fmaxf(a10, 0.f); a11 = fmaxf(a11, 0.f);
  long long ob = ((long long)(n * Cout + co) * Ho + 2 * i) * Wo + 2 * j;
  st2(out + ob, a00, a01);
  st2(out + ob + Wo, a10, a11);
}

extern "C" void kernel_launch(void* const* d_in, const int* in_sizes, int n_in,
                              void* d_out, int out_size, void* d_ws, size_t ws_size,
                              hipStream_t stream) {
  const float* x   = (const float*)d_in[0];
  const float* ew0 = (const float*)d_in[1];  const float* eb0 = (const float*)d_in[2];
  const float* ew1 = (const float*)d_in[3];  const float* eb1 = (const float*)d_in[4];
  const float* ew2 = (const float*)d_in[5];  const float* eb2 = (const float*)d_in[6];
  const float* pw  = (const float*)d_in[7];  const float* pb  = (const float*)d_in[8];
  const float* dw0 = (const float*)d_in[9];  const float* db0 = (const float*)d_in[10];
  const float* dw1 = (const float*)d_in[11]; const float* db1 = (const float*)d_in[12];
  const float* dw2 = (const float*)d_in[13]; const float* db2 = (const float*)d_in[14];
  const float* ow  = (const float*)d_in[15]; const float* ob  = (const float*)d_in[16];
  const float* emb = (const float*)d_in[17];

  float* out   = (float*)d_out;
  float* recon = out;
  float* z     = out + 1572864;
  float* zq    = out + 3670016;
  float* resid = out + 5767168;
  float* codes = out + 14155776;

  char* ws = (char*)d_ws;
  dim3 blk(256);
  auto g = [](long long tot) { return dim3((unsigned)((tot + 255) / 256)); };

  // ---- main-path workspace plan (~204.5 MB) ----
  const size_t OFF_S1IN  = 0ULL;                    // 4,734,976   [8][34][34][256] bf16
  const size_t OFF_S1OUT = 4734976ULL;              // 35,684,352  [8][66][66][512] bf16
  const size_t OFF_WP1   = 40419328ULL;             // 4,194,304
  const size_t OFF_WP2   = 44613632ULL;             // 4,194,304 (ends 48,807,936)
  const size_t OFF_E0    = 0ULL;                    // encoder f32 67,108,864 (dead later)
  const size_t OFF_E1    = 67108864ULL;             // 33,554,432 (ends 100,663,296)
  const size_t OFF_E2    = 0ULL;                    // 16,777,216
  const size_t OFF_DD2   = 0ULL;                    // 134,217,728 [8][128][256][256] bf16
  const size_t OFF_S2OUT = 134217728ULL;            // 69,222,400  [8][130][130][256] bf16
  const size_t OFF_WP3   = 203440128ULL;            // 1,048,576
  const size_t OFF_EN    = 204488704ULL;            // 16,384
  const size_t WS_NEED   = 204505088ULL;

  if (ws_size >= WS_NEED) {
    float* e0 = (float*)(ws + OFF_E0);
    float* e1 = (float*)(ws + OFF_E1);
    float* e2 = (float*)(ws + OFF_E2);
    float* en = (float*)(ws + OFF_EN);
    unsigned short* s1in  = (unsigned short*)(ws + OFF_S1IN);
    unsigned short* s1out = (unsigned short*)(ws + OFF_S1OUT);
    unsigned short* s2out = (unsigned short*)(ws + OFF_S2OUT);
    unsigned short* dd2   = (unsigned short*)(ws + OFF_DD2);
    unsigned short* wp1   = (unsigned short*)(ws + OFF_WP1);
    unsigned short* wp2   = (unsigned short*)(ws + OFF_WP2);
    unsigned short* wp3   = (unsigned short*)(ws + OFF_WP3);

    emb_norms<<<g(4096), blk, 0, stream>>>(emb, en);

    // encoder (fp32, bit-identical accumulation order)
    conv4s2_v2<<<g(8LL * 32 * 64 * 64), blk, 0, stream>>>(x, ew0, eb0, e0, 3, 128, 256, 256, 1);
    conv4s2_v2<<<g(8LL * 64 * 32 * 32), blk, 0, stream>>>(e0, ew1, eb1, e1, 128, 256, 128, 128, 1);
    conv4s2_v2<<<g(8LL * 128 * 16 * 16), blk, 0, stream>>>(e1, ew2, eb2, e2, 256, 512, 64, 64, 1);
    conv1x1<<<g(8LL * 64 * 1024), blk, 0, stream>>>(e2, pw, pb, z, 512, 256);

    // residual quantization
    rq_kernel2<<<dim3(256), blk, 0, stream>>>(z, emb, en, zq, resid, codes);

    // decoder prep
    hipMemsetAsync(ws + OFF_S1IN, 0, 4734976ULL, stream);
    hipMemsetAsync(ws + OFF_S1OUT, 0, 35684352ULL, stream);
    hipMemsetAsync(ws + OFF_S2OUT, 0, 69222400ULL, stream);
    to_nhwc_s1<<<dim3(2048), blk, 0, stream>>>(zq, s1in);
    wprep_k<<<g(16LL * 256 * 512), blk, 0, stream>>>(dw0, wp1, 256, 512);
    wprep_k<<<g(16LL * 512 * 256), blk, 0, stream>>>(dw1, wp2, 512, 256);
    wprep_k<<<g(16LL * 256 * 128), blk, 0, stream>>>(dw2, wp3, 256, 128);

    // decoder MFMA stages
    convt_mfma<256, 512, 4, 32, 32, 32, 4, false>
        <<<dim3(64, 4, 4), dim3(256), 0, stream>>>(s1in, wp1, db0, s1out);
    convt_mfma<512, 256, 4, 64, 64, 64, 8, false>
        <<<dim3(128, 2, 4), dim3(512), 0, stream>>>(s1out, wp2, db1, s2out);
    convt_mfma<256, 128, 4, 64, 128, 128, 8, true>
        <<<dim3(512, 1, 4), dim3(512), 0, stream>>>(s2out, wp3, db2, dd2);

    conv3x3_out<<<g(8LL * 3 * 256 * 256), blk, 0, stream>>>(
        (const __hip_bfloat16*)dd2, ow, ob, recon);
  } else {
    // ---- fallback: round-2 layout/path ----
    const size_t OFF_A = 65536ULL;
    const size_t OFF_B = 65536ULL + 67108864ULL;
    float* en = (float*)(ws);
    float* e0 = (float*)(ws + OFF_A);
    float* e1 = (float*)(ws + OFF_B);
    float* e2 = (float*)(ws + OFF_A);
    __hip_bfloat16* dd0 = (__hip_bfloat16*)(ws + OFF_B);
    __hip_bfloat16* dd1 = (__hip_bfloat16*)(ws + OFF_A);
    __hip_bfloat16* dd2 = (__hip_bfloat16*)(ws + OFF_B);

    emb_norms<<<g(4096), blk, 0, stream>>>(emb, en);
    conv4s2_v2<<<g(8LL * 32 * 64 * 64), blk, 0, stream>>>(x, ew0, eb0, e0, 3, 128, 256, 256, 1);
    conv4s2_v2<<<g(8LL * 64 * 32 * 32), blk, 0, stream>>>(e0, ew1, eb1, e1, 128, 256, 128, 128, 1);
    conv4s2_v2<<<g(8LL * 128 * 16 * 16), blk, 0, stream>>>(e1, ew2, eb2, e2, 256, 512, 64, 64, 1);
    conv1x1<<<g(8LL * 64 * 1024), blk, 0, stream>>>(e2, pw, pb, z, 512, 256);
    rq_kernel2<<<dim3(256), blk, 0, stream>>>(z, emb, en, zq, resid, codes);
    convT4s2_relu<float, __hip_bfloat16>
        <<<g(8LL * 512 * 32 * 32), blk, 0, stream>>>(zq, dw0, db0, dd0, 256, 512, 32, 32);
    convT4s2_relu<__hip_bfloat16, __hip_bfloat16>
        <<<g(8LL * 256 * 64 * 64), blk, 0, stream>>>(dd0, dw1, db1, dd1, 512, 256, 64, 64);
    convT4s2_relu<__hip_bfloat16, __hip_bfloat16>
        <<<g(8LL * 128 * 128 * 128), blk, 0, stream>>>(dd1, dw2, db2, dd2, 256, 128, 128, 128);
    conv3x3_out<<<g(8LL * 3 * 256 * 256), blk, 0, stream>>>(dd2, ow, ob, recon);
  }
}

// Round 4
// 4047.811 us; speedup vs baseline: 14.1479x; 1.7603x over previous
//
#include <hip/hip_runtime.h>
#include <hip/hip_bf16.h>
#include <cstdint>

#define BATCH 8
#define LATC 256
#define NCODE 1024
#define NLVL 4

typedef __attribute__((ext_vector_type(8))) short bf16x8v;
typedef __attribute__((ext_vector_type(4))) float f32x4v;

__device__ __forceinline__ unsigned short f2b(float f) {
  __hip_bfloat16 h = __float2bfloat16(f);
  return *reinterpret_cast<unsigned short*>(&h);
}

// async global->LDS 16B: LDS base = readfirstlane(lane0 offset), HW writes base + lane*16
__device__ __forceinline__ void gl_lds16(const void* gptr, unsigned lds_byte_off) {
  unsigned m0v = __builtin_amdgcn_readfirstlane(lds_byte_off);
  asm volatile("s_mov_b32 m0, %0\n"
               "global_load_lds_dwordx4 %1, off\n" ::"s"(m0v), "v"(gptr)
               : "memory");
}

// ================= encoder conv k4 s2 p1 (+relu), LDS-tiled, bit-exact FMA chain =================
// Block: 16x16 output px tile. 4 waves; each wave covers the whole px tile (lane = 2x2 px)
// and owns a (CO_TILE/4)-wide cout slice. Input staged in LDS per CI_CHUNK; weights via
// scalar loads (readfirstlane-uniform pointer). FMA order per output: ci asc, kh, kw  — identical
// to the round-2/3 kernels => z bit-identical => codes safe.
template <int CIN, int COUT, int HIN, int CI_CHUNK, int CO_TILE>
__global__ __launch_bounds__(256) void conv_enc(
    const float* __restrict__ in, const float* __restrict__ w,
    const float* __restrict__ bias, float* __restrict__ out) {
  constexpr int WIN = HIN;
  constexpr int HOUT = HIN / 2, WOUT = WIN / 2;
  constexpr int PT1 = HOUT / 16;
  constexpr int CPW = CO_TILE / 4;   // couts per wave
  constexpr int CL = CPW / 4;        // groups of 4 couts per wave
  constexpr int NEL = CI_CHUNK * 34 * 34;

  __shared__ float T[CI_CHUNK][34][35];

  const int tid = threadIdx.x;
  const int lane = tid & 63;
  const int wv = __builtin_amdgcn_readfirstlane(tid >> 6);  // 0..3, SGPR
  const int opy = (lane >> 3) << 1;  // 0..14 output-row offset (2 rows per lane)
  const int opx = (lane & 7) << 1;   // 0..14 output-col offset

  const int bx = blockIdx.x;
  const int n = bx / (PT1 * PT1);
  const int pt = bx % (PT1 * PT1);
  const int oh0 = (pt / PT1) * 16, ow0 = (pt % PT1) * 16;
  const int hbase = 2 * oh0 - 1, wbase = 2 * ow0 - 1;
  const int co_base = blockIdx.y * CO_TILE + wv * CPW;

  float acc[CL][4][2][2];
#pragma unroll
  for (int cl = 0; cl < CL; ++cl)
#pragma unroll
    for (int j = 0; j < 4; ++j) {
      float b = bias[co_base + cl * 4 + j];
      acc[cl][j][0][0] = b; acc[cl][j][0][1] = b;
      acc[cl][j][1][0] = b; acc[cl][j][1][1] = b;
    }

  for (int ch = 0; ch < CIN; ch += CI_CHUNK) {
    for (int u = tid; u < NEL; u += 256) {
      int cir = u / (34 * 34);
      int rem = u % (34 * 34);
      int r = rem / 34, c = rem % 34;
      int hi = hbase + r, wi = wbase + c;
      float v = 0.f;
      if ((unsigned)hi < (unsigned)HIN && (unsigned)wi < (unsigned)WIN)
        v = in[((long long)(n * CIN + ch + cir) * HIN + hi) * WIN + wi];
      T[cir][r][c] = v;
    }
    __syncthreads();
#pragma unroll
    for (int cir = 0; cir < CI_CHUNK; ++cir) {
      float xv[6][6];
#pragma unroll
      for (int r = 0; r < 6; ++r)
#pragma unroll
        for (int c = 0; c < 6; ++c) xv[r][c] = T[cir][2 * opy + r][2 * opx + c];
      // wait: T row = 2*(opy+dy)+kh - but opy is ALREADY the output-row offset; input row
      // offset = 2*opy + (2*dy+kh) = 2*opy + r. However 2*opy can reach 28, +5 = 33. OK.
#pragma unroll
      for (int cl = 0; cl < CL; ++cl)
#pragma unroll
        for (int j = 0; j < 4; ++j) {
          const float* __restrict__ wp =
              w + ((long long)(co_base + cl * 4 + j) * CIN + (ch + cir)) * 16;
#pragma unroll
          for (int kh = 0; kh < 4; ++kh)
#pragma unroll
            for (int kw = 0; kw < 4; ++kw) {
              float wt = wp[kh * 4 + kw];
#pragma unroll
              for (int dy = 0; dy < 2; ++dy)
#pragma unroll
                for (int dx = 0; dx < 2; ++dx)
                  acc[cl][j][dy][dx] =
                      fmaf(xv[2 * dy + kh][2 * dx + kw], wt, acc[cl][j][dy][dx]);
            }
        }
    }
    __syncthreads();
  }
#pragma unroll
  for (int cl = 0; cl < CL; ++cl)
#pragma unroll
    for (int j = 0; j < 4; ++j) {
      int co = co_base + cl * 4 + j;
#pragma unroll
      for (int dy = 0; dy < 2; ++dy) {
        int oh = oh0 + opy + dy, ow = ow0 + opx;
        float v0 = fmaxf(acc[cl][j][dy][0], 0.f);
        float v1 = fmaxf(acc[cl][j][dy][1], 0.f);
        *reinterpret_cast<float2*>(
            &out[((long long)(n * COUT + co) * HOUT + oh) * WOUT + ow]) =
            make_float2(v0, v1);
      }
    }
}

// 2*opy fix note: opy in [0,14] step 2 => 2*opy in [0,28] step 4; rows used 2*opy..2*opy+5 <= 33. OK.

// ---------------- weight transpose for 1x1 conv: [256co][512ci] -> [512ci][256co] ----------------
__global__ __launch_bounds__(256) void wtrans(const float* __restrict__ pw,
                                              float* __restrict__ pwT) {
  int gid = blockIdx.x * 256 + threadIdx.x;
  if (gid >= 512 * 256) return;
  int ci = gid >> 8, co = gid & 255;
  pwT[gid] = pw[co * 512 + ci];
}

// ---------------- 1x1 conv as GEMM: 64co x 128px per block, LDS px staging ----------------
__global__ __launch_bounds__(256) void conv1x1_v2(
    const float* __restrict__ in, const float* __restrict__ pwT,
    const float* __restrict__ bias, float* __restrict__ out) {
  __shared__ float Tx[16][128];
  const int tid = threadIdx.x;
  const int lane = tid & 63;
  const int wv = __builtin_amdgcn_readfirstlane(tid >> 6);
  const int p0 = lane * 2;
  const int bx = blockIdx.x;
  const int n = bx >> 3, pxb = bx & 7;
  const int px_base = pxb * 128;
  const int co_base = blockIdx.y * 64 + wv * 16;

  float acc[4][4][2];
#pragma unroll
  for (int cl = 0; cl < 4; ++cl)
#pragma unroll
    for (int j = 0; j < 4; ++j) {
      float b = bias[co_base + cl * 4 + j];
      acc[cl][j][0] = b; acc[cl][j][1] = b;
    }

  for (int ch = 0; ch < 512; ch += 16) {
    for (int u = tid; u < 2048; u += 256) {
      int cir = u >> 7, p = u & 127;
      Tx[cir][p] = in[(long long)(n * 512 + ch + cir) * 1024 + px_base + p];
    }
    __syncthreads();
#pragma unroll
    for (int cir = 0; cir < 16; ++cir) {
      float2 xv = *reinterpret_cast<const float2*>(&Tx[cir][p0]);
#pragma unroll
      for (int cl = 0; cl < 4; ++cl) {
        const float* __restrict__ wp = pwT + (ch + cir) * 256 + co_base + cl * 4;
#pragma unroll
        for (int j = 0; j < 4; ++j) {
          float wt = wp[j];
          acc[cl][j][0] = fmaf(xv.x, wt, acc[cl][j][0]);
          acc[cl][j][1] = fmaf(xv.y, wt, acc[cl][j][1]);
        }
      }
    }
    __syncthreads();
  }
#pragma unroll
  for (int cl = 0; cl < 4; ++cl)
#pragma unroll
    for (int j = 0; j < 4; ++j) {
      int co = co_base + cl * 4 + j;
      *reinterpret_cast<float2*>(&out[(long long)(n * 256 + co) * 1024 + px_base + p0]) =
          make_float2(acc[cl][j][0], acc[cl][j][1]);
    }
}

// ---------------- per-code squared norms ----------------
__global__ __launch_bounds__(256) void emb_norms(
    const float* __restrict__ emb, float* __restrict__ en) {
  int k = blockIdx.x * blockDim.x + threadIdx.x;
  if (k >= NLVL * NCODE) return;
  const float* __restrict__ e = emb + (long long)k * LATC;
  float s = 0.f;
  for (int c = 0; c < LATC; ++c) s = fmaf(e[c], e[c], s);
  en[k] = s;
}

// ---------------- residual quantization v2 (unchanged from round 3) ----------------
#define RQ_P 32
#define RQ_CT 32
#define RQ_RS 260

__global__ __launch_bounds__(256) void rq_kernel2(
    const float* __restrict__ z, const float* __restrict__ emb,
    const float* __restrict__ en, float* __restrict__ zq_out,
    float* __restrict__ resid_out, float* __restrict__ codes_out) {
  __shared__ float e_sh[RQ_CT * RQ_RS];
  __shared__ float r_sh[RQ_P * RQ_RS];
  __shared__ float sum_sh[RQ_P];
  __shared__ int code_sh[RQ_P];
  const int tid = threadIdx.x;
  const int blk = blockIdx.x;
  const int n = (blk * RQ_P) >> 10;
  const int hw0 = (blk * RQ_P) & 1023;
  const long long zb = ((long long)n * LATC) * 1024 + hw0;

  for (int it = 0; it < 32; ++it) {
    int u = it * 256 + tid;
    int c = u >> 5, pix = u & 31;
    float v = z[zb + (long long)c * 1024 + pix];
    r_sh[pix * RQ_RS + c] = v;
    resid_out[((long long)n * LATC + c) * 1024 + hw0 + pix] = v;
  }
  __syncthreads();

  const int code_l = tid & 31;
  const int pixoff = tid >> 5;
  const int upix = tid >> 3;
  const int ucg = tid & 7;

  for (int l = 0; l < NLVL; ++l) {
    {
      float s = 0.f;
#pragma unroll
      for (int it = 0; it < 8; ++it) {
        int c4 = ucg + it * 8;
        float4 r4 = *(const float4*)&r_sh[upix * RQ_RS + c4 * 4];
        s += r4.x * r4.x + r4.y * r4.y + r4.z * r4.z + r4.w * r4.w;
      }
      s += __shfl_xor(s, 1); s += __shfl_xor(s, 2); s += __shfl_xor(s, 4);
      if (ucg == 0) sum_sh[upix] = s;
    }
    __syncthreads();
    const float* __restrict__ E = emb + (long long)l * NCODE * LATC;
    const float* __restrict__ enl = en + l * NCODE;
    float best[4]; int bidx[4];
#pragma unroll
    for (int g = 0; g < 4; ++g) { best[g] = 3.4e38f; bidx[g] = 0; }
    for (int tile = 0; tile < NCODE / RQ_CT; ++tile) {
      const float* __restrict__ Et = E + (long long)tile * RQ_CT * LATC;
      for (int it = 0; it < 32; ++it) {
        int u = it * 256 + tid;
        int cc = u >> 8, ch = u & 255;
        e_sh[cc * RQ_RS + ch] = Et[cc * LATC + ch];
      }
      __syncthreads();
      float acc[4] = {0.f, 0.f, 0.f, 0.f};
      for (int c4 = 0; c4 < 64; ++c4) {
        float4 e4 = *(const float4*)&e_sh[code_l * RQ_RS + c4 * 4];
#pragma unroll
        for (int g = 0; g < 4; ++g) {
          float4 r4 = *(const float4*)&r_sh[(g * 8 + pixoff) * RQ_RS + c4 * 4];
          acc[g] = fmaf(r4.x, e4.x, acc[g]);
          acc[g] = fmaf(r4.y, e4.y, acc[g]);
          acc[g] = fmaf(r4.z, e4.z, acc[g]);
          acc[g] = fmaf(r4.w, e4.w, acc[g]);
        }
      }
      int code = tile * RQ_CT + code_l;
      float ek2 = enl[code];
#pragma unroll
      for (int g = 0; g < 4; ++g) {
        float d2 = (sum_sh[g * 8 + pixoff] - 2.f * acc[g]) + ek2;
        if (d2 < best[g]) { best[g] = d2; bidx[g] = code; }
      }
      __syncthreads();
    }
#pragma unroll
    for (int g = 0; g < 4; ++g) {
      float bd = best[g]; int bi = bidx[g];
#pragma unroll
      for (int m = 1; m < 32; m <<= 1) {
        float od = __shfl_xor(bd, m);
        int oi = __shfl_xor(bi, m);
        if (od < bd || (od == bd && oi < bi)) { bd = od; bi = oi; }
      }
      if (code_l == 0) {
        int pix = g * 8 + pixoff;
        code_sh[pix] = bi;
        codes_out[(long long)(l * BATCH + n) * 1024 + hw0 + pix] = (float)bi;
      }
    }
    __syncthreads();
    {
      int sel = code_sh[upix];
      const float* __restrict__ esel = E + (long long)sel * LATC;
#pragma unroll
      for (int it = 0; it < 8; ++it) {
        int c4 = ucg + it * 8;
        float4 r4 = *(const float4*)&r_sh[upix * RQ_RS + c4 * 4];
        float4 e4 = *(const float4*)&esel[c4 * 4];
        r4.x -= e4.x; r4.y -= e4.y; r4.z -= e4.z; r4.w -= e4.w;
        *(float4*)&r_sh[upix * RQ_RS + c4 * 4] = r4;
        if (l < NLVL - 1) {
          long long rb = ((long long)((l + 1) * BATCH + n) * LATC + c4 * 4) * 1024 + hw0 + upix;
          resid_out[rb] = r4.x;
          resid_out[rb + 1024] = r4.y;
          resid_out[rb + 2048] = r4.z;
          resid_out[rb + 3072] = r4.w;
        }
      }
    }
    __syncthreads();
  }
  for (int it = 0; it < 32; ++it) {
    int u = it * 256 + tid;
    int c = u >> 5, pix = u & 31;
    float zv = z[zb + (long long)c * 1024 + pix];
    zq_out[zb + (long long)c * 1024 + pix] = zv - r_sh[pix * RQ_RS + c];
  }
}

// ---------------- zq (NCHW f32) -> padded NHWC bf16 [8][34][34][256] ----------------
__global__ __launch_bounds__(256) void to_nhwc_s1(const float* __restrict__ zq,
                                                  unsigned short* __restrict__ o) {
  __shared__ float tsh[32][33];
  int bx = blockIdx.x;
  int ct = bx & 7, y = (bx >> 3) & 31, n = bx >> 8;
  int tid = threadIdx.x;
  int x = tid & 31, cl = tid >> 5;
#pragma unroll
  for (int it = 0; it < 4; ++it) {
    int ci = it * 8 + cl;
    tsh[ci][x] = zq[((long long)(n * 256 + ct * 32 + ci) * 32 + y) * 32 + x];
  }
  __syncthreads();
  int ci = tid & 31, xg = tid >> 5;
#pragma unroll
  for (int it = 0; it < 4; ++it) {
    int xw = it * 8 + xg;
    o[(((long long)n * 34 + y + 1) * 34 + xw + 1) * 256 + ct * 32 + ci] = f2b(tsh[ci][xw]);
  }
}

// ---------------- weight prep: HWIO f32 -> [4ph][CIN/32][4tap][COUT][32] bf16 ----------------
__global__ __launch_bounds__(256) void wprep_k(const float* __restrict__ w,
                                               unsigned short* __restrict__ o,
                                               int CINc, int COUTc) {
  long long total = 16LL * CINc * COUTc;
  long long gid = (long long)blockIdx.x * 256 + threadIdx.x;
  if (gid >= total) return;
  int ci32 = (int)(gid & 31); long long t = gid >> 5;
  int co = (int)(t % COUTc); t /= COUTc;
  int tap = (int)(t & 3); t >>= 2;
  int nch = CINc / 32;
  int ch = (int)(t % nch); int phase = (int)(t / nch);
  int py = phase >> 1, px = phase & 1;
  int ky = py + 2 * (tap >> 1), kx = px + 2 * (tap & 1);
  int ci = ch * 32 + ci32;
  float v = w[(((long long)ky * 4 + kx) * CINc + ci) * COUTc + co];
  o[gid] = f2b(v);
}

// ---------------- transposed conv k4 s2 via MFMA implicit GEMM (unchanged) ----------------
template <int CIN, int COUT, int TH, int TW, int Hi, int Wi, int NW, bool OUT_NCHW>
__global__ __launch_bounds__(NW * 64) void convt_mfma(
    const unsigned short* __restrict__ xin, const unsigned short* __restrict__ wprep,
    const float* __restrict__ bias, unsigned short* __restrict__ outp) {
  constexpr int TWP = TW + 2;
  constexpr int Hp = Hi + 2, Wp = Wi + 2;
  constexpr int NCH = CIN / 32;
  constexpr int TPB = NW * 64;
  constexpr int XU = (TH + 2) * TWP * 4;
  constexpr int XUP = ((XU + TPB - 1) / TPB) * TPB;
  __shared__ unsigned short xlds[2][XUP * 8];
  __shared__ unsigned short wlds[2][4 * 128 * 32];

  const int tid = threadIdx.x;
  const int w = tid >> 6, lane = tid & 63;
  const int l15 = lane & 15, seg = lane >> 4;

  constexpr int SW = Wi / TW, SH = Hi / TH;
  int bx = blockIdx.x;
  int n = bx / (SH * SW); int srem = bx % (SH * SW);
  int i0 = (srem / SW) * TH, j0 = (srem % SW) * TW;
  int cob0 = blockIdx.y * 128;
  int phase = blockIdx.z; int py = phase >> 1, px = phase & 1;

  int wpix, wco;
  if (NW == 8) { wpix = w & 3; wco = w >> 2; }
  else { wpix = w & 1; wco = w >> 1; }

  const unsigned short* xsrc = xin + (long long)n * Hp * Wp * CIN;

  f32x4v acc[4][4];
  if (!OUT_NCHW) {
#pragma unroll
    for (int b = 0; b < 4; ++b) {
      float bv = bias[cob0 + (wco * 4 + b) * 16 + l15];
      f32x4v v = {bv, bv, bv, bv};
#pragma unroll
      for (int a = 0; a < 4; ++a) acc[a][b] = v;
    }
  } else {
#pragma unroll
    for (int a = 0; a < 4; ++a) {
      f32x4v v;
#pragma unroll
      for (int q = 0; q < 4; ++q) v[q] = bias[cob0 + (wco * 4 + a) * 16 + seg * 4 + q];
#pragma unroll
      for (int b = 0; b < 4; ++b) acc[a][b] = v;
    }
  }

  auto stageX = [&](int buf, int ch) {
#pragma unroll
    for (int it = 0; it < XUP / TPB; ++it) {
      int u = it * TPB + tid;
      int us = u < XU ? u : XU - 1;
      int row = us / (TWP * 4);
      int rem = us - row * (TWP * 4);
      int col = rem >> 2, sg = rem & 3;
      const unsigned short* g =
          xsrc + (((long long)(i0 + row) * Wp) + (j0 + col)) * CIN + ch * 32 + sg * 8;
      gl_lds16(g, (unsigned)(unsigned long long)(const void*)&xlds[buf][u * 8]);
    }
  };
  auto stageW = [&](int buf, int ch) {
    const unsigned short* wb = wprep + (((long long)phase * NCH + ch) * 4) * COUT * 32;
#pragma unroll
    for (int it = 0; it < 2048 / TPB; ++it) {
      int u = it * TPB + tid;
      int tap = u >> 9;
      int rem = u & 511;
      int co = rem >> 2, sg = rem & 3;
      gl_lds16(wb + ((long long)tap * COUT + cob0 + co) * 32 + sg * 8,
               (unsigned)(unsigned long long)(const void*)&wlds[buf][u * 8]);
    }
  };
  auto compute = [&](int buf) {
#pragma unroll
    for (int t = 0; t < 4; ++t) {
      int oy = (t >> 1) - 1 + py, ox = (t & 1) - 1 + px;
      bf16x8v xf[4], wf[4];
#pragma unroll
      for (int i = 0; i < 4; ++i) {
        int pl = (wpix * 4 + i) * 16 + l15;
        int r = pl / TW, c = pl % TW;
        int xrow = r + oy + 1, xcol = c + ox + 1;
        xf[i] = *(const bf16x8v*)&xlds[buf][(xrow * TWP + xcol) * 32 + seg * 8];
        int co = (wco * 4 + i) * 16 + l15;
        wf[i] = *(const bf16x8v*)&wlds[buf][(t * 128 + co) * 32 + seg * 8];
      }
#pragma unroll
      for (int a = 0; a < 4; ++a)
#pragma unroll
        for (int b = 0; b < 4; ++b) {
          if (OUT_NCHW)
            acc[a][b] = __builtin_amdgcn_mfma_f32_16x16x32_bf16(wf[a], xf[b], acc[a][b], 0, 0, 0);
          else
            acc[a][b] = __builtin_amdgcn_mfma_f32_16x16x32_bf16(xf[a], wf[b], acc[a][b], 0, 0, 0);
        }
    }
  };

  stageX(0, 0); stageW(0, 0);
  asm volatile("s_waitcnt vmcnt(0)" ::: "memory");
  __syncthreads();
  for (int ch = 0; ch < NCH; ++ch) {
    int cur = ch & 1;
    if (ch + 1 < NCH) { stageX(cur ^ 1, ch + 1); stageW(cur ^ 1, ch + 1); }
    compute(cur);
    asm volatile("s_waitcnt vmcnt(0)" ::: "memory");
    __syncthreads();
  }

  if (!OUT_NCHW) {
    constexpr int Wpo = 2 * Wi + 2;
    long long ob_n = (long long)n * (2 * Hi + 2) * Wpo * COUT;
#pragma unroll
    for (int a = 0; a < 4; ++a)
#pragma unroll
      for (int q = 0; q < 4; ++q) {
        int pl = (wpix * 4 + a) * 16 + seg * 4 + q;
        int r = pl / TW, c = pl % TW;
        int yo = 2 * (i0 + r) + py + 1, xo = 2 * (j0 + c) + px + 1;
        long long ob = ob_n + ((long long)yo * Wpo + xo) * COUT + cob0;
#pragma unroll
        for (int b = 0; b < 4; ++b) {
          float v = fmaxf(acc[a][b][q], 0.f);
          outp[ob + (wco * 4 + b) * 16 + l15] = f2b(v);
        }
      }
  } else {
    constexpr int Ho = 2 * Hi, Wo = 2 * Wi;
#pragma unroll
    for (int a = 0; a < 4; ++a)
#pragma unroll
      for (int q = 0; q < 4; ++q) {
        int co = cob0 + (wco * 4 + a) * 16 + seg * 4 + q;
#pragma unroll
        for (int b = 0; b < 4; ++b) {
          int pl = (wpix * 4 + b) * 16 + l15;
          int r = pl / TW, c = pl % TW;
          int yo = 2 * (i0 + r) + py, xo = 2 * (j0 + c) + px;
          float v = fmaxf(acc[a][b][q], 0.f);
          outp[((long long)(n * COUT + co) * Ho + yo) * Wo + xo] = f2b(v);
        }
      }
  }
}

// ---------------- final 3x3 conv s1 p1, bf16 NCHW in, f32 out ----------------
__global__ __launch_bounds__(256) void conv3x3_out(
    const __hip_bfloat16* __restrict__ in, const float* __restrict__ w,
    const float* __restrict__ bias, float* __restrict__ out) {
  const int Cin = 128, H = 256, W = 256, Cout = 3;
  long long total = (long long)BATCH * Cout * H * W;
  long long gid = (long long)blockIdx.x * blockDim.x + threadIdx.x;
  if (gid >= total) return;
  int x = (int)(gid % W); long long t = gid / W;
  int y = (int)(t % H); t /= H;
  int co = (int)(t % Cout); int n = (int)(t / Cout);
  float acc = bias[co];
  for (int ci = 0; ci < Cin; ++ci) {
    const __hip_bfloat16* __restrict__ ip = in + ((long long)(n * Cin + ci) * H) * W;
    const float* __restrict__ wp = w + ((long long)(co * Cin + ci)) * 9;
#pragma unroll
    for (int kh = 0; kh < 3; ++kh) {
      int yy = y + kh - 1;
      if ((unsigned)yy >= (unsigned)H) continue;
#pragma unroll
      for (int kw = 0; kw < 3; ++kw) {
        int xx = x + kw - 1;
        if ((unsigned)xx >= (unsigned)W) continue;
        acc = fmaf(__bfloat162float(ip[(long long)yy * W + xx]), wp[kh * 3 + kw], acc);
      }
    }
  }
  out[gid] = acc;
}

// ---------------- fallback helpers + scalar kernels (round-2/3 path) ----------------
__device__ __forceinline__ float ldf(const float* p, long long i) { return p[i]; }
__device__ __forceinline__ float ldf(const __hip_bfloat16* p, long long i) {
  return __bfloat162float(p[i]);
}
__device__ __forceinline__ void st2(float* p, float a, float b) {
  *reinterpret_cast<float2*>(p) = make_float2(a, b);
}
__device__ __forceinline__ void st2(__hip_bfloat16* p, float a, float b) {
  __hip_bfloat162 v;
  v.x = __float2bfloat16(a); v.y = __float2bfloat16(b);
  *reinterpret_cast<__hip_bfloat162*>(p) = v;
}

__global__ __launch_bounds__(256) void conv4s2_v2(
    const float* __restrict__ in, const float* __restrict__ w,
    const float* __restrict__ bias, float* __restrict__ out,
    int Cin, int Cout, int Hin, int Win, int relu) {
  const int Hout = Hin >> 1, Wout = Win >> 1;
  const int H2 = Hout >> 1, W2 = Wout >> 1;
  const int cogn = Cout >> 2;
  long long total = (long long)BATCH * cogn * H2 * W2;
  long long gid = (long long)blockIdx.x * blockDim.x + threadIdx.x;
  if (gid >= total) return;
  int w2 = (int)(gid % W2); long long t = gid / W2;
  int h2 = (int)(t % H2); t /= H2;
  int cog = (int)(t % cogn); int n = (int)(t / cogn);
  int co0 = cog << 2;
  float a[4][2][2];
#pragma unroll
  for (int j = 0; j < 4; ++j) {
    float b = bias[co0 + j];
    a[j][0][0] = b; a[j][0][1] = b; a[j][1][0] = b; a[j][1][1] = b;
  }
  const int hi0 = 4 * h2 - 1, wi0 = 4 * w2 - 1;
  const long long wstride = (long long)Cin * 16;
  for (int ci = 0; ci < Cin; ++ci) {
    const float* __restrict__ ip = in + ((long long)(n * Cin + ci) * Hin) * Win;
    float xv[6][6];
#pragma unroll
    for (int r = 0; r < 6; ++r) {
      int hi = hi0 + r;
      bool ok = (unsigned)hi < (unsigned)Hin;
#pragma unroll
      for (int c = 0; c < 6; ++c) {
        int wi = wi0 + c;
        xv[r][c] = (ok && (unsigned)wi < (unsigned)Win) ? ip[(long long)hi * Win + wi] : 0.f;
      }
    }
    const float* __restrict__ wp = w + (long long)co0 * wstride + (long long)ci * 16;
#pragma unroll
    for (int kh = 0; kh < 4; ++kh) {
#pragma unroll
      for (int kw = 0; kw < 4; ++kw) {
        int k = (kh << 2) + kw;
        float w0 = wp[k], w1 = wp[wstride + k], w2v = wp[2 * wstride + k], w3 = wp[3 * wstride + k];
#pragma unroll
        for (int dy = 0; dy < 2; ++dy)
#pragma unroll
          for (int dx = 0; dx < 2; ++dx) {
            float v = xv[2 * dy + kh][2 * dx + kw];
            a[0][dy][dx] = fmaf(v, w0, a[0][dy][dx]);
            a[1][dy][dx] = fmaf(v, w1, a[1][dy][dx]);
            a[2][dy][dx] = fmaf(v, w2v, a[2][dy][dx]);
            a[3][dy][dx] = fmaf(v, w3, a[3][dy][dx]);
          }
      }
    }
  }
  long long cs = (long long)Hout * Wout;
  long long ob0 = ((long long)(n * Cout + co0) * Hout + 2 * h2) * Wout + 2 * w2;
#pragma unroll
  for (int j = 0; j < 4; ++j)
#pragma unroll
    for (int dy = 0; dy < 2; ++dy)
#pragma unroll
      for (int dx = 0; dx < 2; ++dx) {
        float v = a[j][dy][dx];
        if (relu) v = fmaxf(v, 0.f);
        out[ob0 + j * cs + (long long)dy * Wout + dx] = v;
      }
}

__global__ __launch_bounds__(256) void conv1x1(
    const float* __restrict__ in, const float* __restrict__ w,
    const float* __restrict__ bias, float* __restrict__ out, int Cin, int Cout) {
  const int HW = 1024;
  const int cogn = Cout >> 2;
  long long total = (long long)BATCH * cogn * HW;
  long long gid = (long long)blockIdx.x * blockDim.x + threadIdx.x;
  if (gid >= total) return;
  int hw = (int)(gid % HW); long long t = gid / HW;
  int cog = (int)(t % cogn); int n = (int)(t / cogn);
  int co0 = cog << 2;
  float a0 = bias[co0], a1 = bias[co0 + 1], a2 = bias[co0 + 2], a3 = bias[co0 + 3];
  for (int ci = 0; ci < Cin; ++ci) {
    float v = in[((long long)(n * Cin + ci)) * HW + hw];
    const float* __restrict__ wp = w + (long long)co0 * Cin + ci;
    a0 = fmaf(v, wp[0], a0);
    a1 = fmaf(v, wp[Cin], a1);
    a2 = fmaf(v, wp[2 * Cin], a2);
    a3 = fmaf(v, wp[3 * Cin], a3);
  }
  long long ob = ((long long)(n * Cout + co0)) * HW + hw;
  out[ob] = a0; out[ob + HW] = a1; out[ob + 2 * HW] = a2; out[ob + 3 * HW] = a3;
}

template <typename TI, typename TO>
__global__ __launch_bounds__(256) void convT4s2_relu(
    const TI* __restrict__ in, const float* __restrict__ w,
    const float* __restrict__ bias, TO* __restrict__ out,
    int Cin, int Cout, int Hi, int Wi) {
  const int Ho = Hi << 1, Wo = Wi << 1;
  long long total = (long long)BATCH * Cout * Hi * Wi;
  long long gid = (long long)blockIdx.x * blockDim.x + threadIdx.x;
  if (gid >= total) return;
  int j = (int)(gid % Wi); long long t = gid / Wi;
  int i = (int)(t % Hi); t /= Hi;
  int co = (int)(t % Cout); int n = (int)(t / Cout);
  const float b = bias[co];
  float a00 = b, a01 = b, a10 = b, a11 = b;
  const long long tapstride = (long long)Cin * Cout;
  const float* __restrict__ wbase = w + co;
  for (int ci = 0; ci < Cin; ++ci) {
    const TI* __restrict__ ip = in + ((long long)(n * Cin + ci) * Hi) * Wi;
    float xv[3][3];
#pragma unroll
    for (int dy = 0; dy < 3; ++dy) {
      int y = i - 1 + dy;
      bool yok = (unsigned)y < (unsigned)Hi;
#pragma unroll
      for (int dx = 0; dx < 3; ++dx) {
        int xx = j - 1 + dx;
        xv[dy][dx] = (yok && (unsigned)xx < (unsigned)Wi) ? ldf(ip, (long long)y * Wi + xx) : 0.f;
      }
    }
    const float* __restrict__ wp = wbase + (long long)ci * Cout;
#define WT(kh, kw) wp[((kh) * 4 + (kw)) * tapstride]
    a00 = fmaf(xv[0][0], WT(0, 0), a00); a00 = fmaf(xv[0][1], WT(0, 2), a00);
    a00 = fmaf(xv[1][0], WT(2, 0), a00); a00 = fmaf(xv[1][1], WT(2, 2), a00);
    a01 = fmaf(xv[0][1], WT(0, 1), a01); a01 = fmaf(xv[0][2], WT(0, 3), a01);
    a01 = fmaf(xv[1][1], WT(2, 1), a01); a01 = fmaf(xv[1][2], WT(2, 3), a01);
    a10 = fmaf(xv[1][0], WT(1, 0), a10); a10 = fmaf(xv[1][1], WT(1, 2), a10);
    a10 = fmaf(xv[2][0], WT(3, 0), a10); a10 = fmaf(xv[2][1], WT(3, 2), a10);
    a11 = fmaf(xv[1][1], WT(1, 1), a11); a11 = fmaf(xv[1][2], WT(1, 3), a11);
    a11 = fmaf(xv[2][1], WT(3, 1), a11); a11 = fmaf(xv[2][2], WT(3, 3), a11);
#undef WT
  }
  a00 = fmaxf(a00, 0.f); a01 = fmaxf(a01, 0.f);
  a10 = fmaxf(a10, 0.f); a11 = fmaxf(a11, 0.f);
  long long ob = ((long long)(n * Cout + co) * Ho + 2 * i) * Wo + 2 * j;
  st2(out + ob, a00, a01);
  st2(out + ob + Wo, a10, a11);
}

extern "C" void kernel_launch(void* const* d_in, const int* in_sizes, int n_in,
                              void* d_out, int out_size, void* d_ws, size_t ws_size,
                              hipStream_t stream) {
  const float* x   = (const float*)d_in[0];
  const float* ew0 = (const float*)d_in[1];  const float* eb0 = (const float*)d_in[2];
  const float* ew1 = (const float*)d_in[3];  const float* eb1 = (const float*)d_in[4];
  const float* ew2 = (const float*)d_in[5];  const float* eb2 = (const float*)d_in[6];
  const float* pw  = (const float*)d_in[7];  const float* pb  = (const float*)d_in[8];
  const float* dw0 = (const float*)d_in[9];  const float* db0 = (const float*)d_in[10];
  const float* dw1 = (const float*)d_in[11]; const float* db1 = (const float*)d_in[12];
  const float* dw2 = (const float*)d_in[13]; const float* db2 = (const float*)d_in[14];
  const float* ow  = (const float*)d_in[15]; const float* ob  = (const float*)d_in[16];
  const float* emb = (const float*)d_in[17];

  float* out   = (float*)d_out;
  float* recon = out;
  float* z     = out + 1572864;
  float* zq    = out + 3670016;
  float* resid = out + 5767168;
  float* codes = out + 14155776;

  char* ws = (char*)d_ws;
  dim3 blk(256);
  auto g = [](long long tot) { return dim3((unsigned)((tot + 255) / 256)); };

  // ---- workspace plan (~204.5 MB) ----
  const size_t OFF_S1IN  = 0ULL;
  const size_t OFF_S1OUT = 4734976ULL;
  const size_t OFF_WP1   = 40419328ULL;
  const size_t OFF_WP2   = 44613632ULL;
  const size_t OFF_E0    = 0ULL;
  const size_t OFF_E1    = 67108864ULL;      // e1 region; pwT reuses it after L3
  const size_t OFF_E2    = 0ULL;
  const size_t OFF_PWT   = 67108864ULL;      // 512 KB, lifetime: wtrans..conv1x1
  const size_t OFF_DD2   = 0ULL;
  const size_t OFF_S2OUT = 134217728ULL;
  const size_t OFF_WP3   = 203440128ULL;
  const size_t OFF_EN    = 204488704ULL;
  const size_t WS_NEED   = 204505088ULL;

  if (ws_size >= WS_NEED) {
    float* e0 = (float*)(ws + OFF_E0);
    float* e1 = (float*)(ws + OFF_E1);
    float* e2 = (float*)(ws + OFF_E2);
    float* en = (float*)(ws + OFF_EN);
    float* pwT = (float*)(ws + OFF_PWT);
    unsigned short* s1in  = (unsigned short*)(ws + OFF_S1IN);
    unsigned short* s1out = (unsigned short*)(ws + OFF_S1OUT);
    unsigned short* s2out = (unsigned short*)(ws + OFF_S2OUT);
    unsigned short* dd2   = (unsigned short*)(ws + OFF_DD2);
    unsigned short* wp1   = (unsigned short*)(ws + OFF_WP1);
    unsigned short* wp2   = (unsigned short*)(ws + OFF_WP2);
    unsigned short* wp3   = (unsigned short*)(ws + OFF_WP3);

    emb_norms<<<g(4096), blk, 0, stream>>>(emb, en);

    // encoder: LDS-tiled fp32, FMA chains bit-identical to previous rounds
    conv_enc<3, 128, 256, 3, 64><<<dim3(8 * 64, 2), blk, 0, stream>>>(x, ew0, eb0, e0);
    conv_enc<128, 256, 128, 4, 64><<<dim3(8 * 16, 4), blk, 0, stream>>>(e0, ew1, eb1, e1);
    conv_enc<256, 512, 64, 4, 32><<<dim3(8 * 4, 16), blk, 0, stream>>>(e1, ew2, eb2, e2);
    wtrans<<<g(512 * 256), blk, 0, stream>>>(pw, pwT);
    conv1x1_v2<<<dim3(64, 4), blk, 0, stream>>>(e2, pwT, pb, z);

    // residual quantization
    rq_kernel2<<<dim3(256), blk, 0, stream>>>(z, emb, en, zq, resid, codes);

    // decoder prep
    hipMemsetAsync(ws + OFF_S1IN, 0, 4734976ULL, stream);
    hipMemsetAsync(ws + OFF_S1OUT, 0, 35684352ULL, stream);
    hipMemsetAsync(ws + OFF_S2OUT, 0, 69222400ULL, stream);
    to_nhwc_s1<<<dim3(2048), blk, 0, stream>>>(zq, s1in);
    wprep_k<<<g(16LL * 256 * 512), blk, 0, stream>>>(dw0, wp1, 256, 512);
    wprep_k<<<g(16LL * 512 * 256), blk, 0, stream>>>(dw1, wp2, 512, 256);
    wprep_k<<<g(16LL * 256 * 128), blk, 0, stream>>>(dw2, wp3, 256, 128);

    // decoder MFMA stages
    convt_mfma<256, 512, 4, 32, 32, 32, 4, false>
        <<<dim3(64, 4, 4), dim3(256), 0, stream>>>(s1in, wp1, db0, s1out);
    convt_mfma<512, 256, 4, 64, 64, 64, 8, false>
        <<<dim3(128, 2, 4), dim3(512), 0, stream>>>(s1out, wp2, db1, s2out);
    convt_mfma<256, 128, 4, 64, 128, 128, 8, true>
        <<<dim3(512, 1, 4), dim3(512), 0, stream>>>(s2out, wp3, db2, dd2);

    conv3x3_out<<<g(8LL * 3 * 256 * 256), blk, 0, stream>>>(
        (const __hip_bfloat16*)dd2, ow, ob, recon);
  } else {
    // ---- fallback: round-2 layout/path ----
    const size_t OFF_A = 65536ULL;
    const size_t OFF_B = 65536ULL + 67108864ULL;
    float* en = (float*)(ws);
    float* e0 = (float*)(ws + OFF_A);
    float* e1 = (float*)(ws + OFF_B);
    float* e2 = (float*)(ws + OFF_A);
    __hip_bfloat16* dd0 = (__hip_bfloat16*)(ws + OFF_B);
    __hip_bfloat16* dd1 = (__hip_bfloat16*)(ws + OFF_A);
    __hip_bfloat16* dd2 = (__hip_bfloat16*)(ws + OFF_B);

    emb_norms<<<g(4096), blk, 0, stream>>>(emb, en);
    conv4s2_v2<<<g(8LL * 32 * 64 * 64), blk, 0, stream>>>(x, ew0, eb0, e0, 3, 128, 256, 256, 1);
    conv4s2_v2<<<g(8LL * 64 * 32 * 32), blk, 0, stream>>>(e0, ew1, eb1, e1, 128, 256, 128, 128, 1);
    conv4s2_v2<<<g(8LL * 128 * 16 * 16), blk, 0, stream>>>(e1, ew2, eb2, e2, 256, 512, 64, 64, 1);
    conv1x1<<<g(8LL * 64 * 1024), blk, 0, stream>>>(e2, pw, pb, z, 512, 256);
    rq_kernel2<<<dim3(256), blk, 0, stream>>>(z, emb, en, zq, resid, codes);
    convT4s2_relu<float, __hip_bfloat16>
        <<<g(8LL * 512 * 32 * 32), blk, 0, stream>>>(zq, dw0, db0, dd0, 256, 512, 32, 32);
    convT4s2_relu<__hip_bfloat16, __hip_bfloat16>
        <<<g(8LL * 256 * 64 * 64), blk, 0, stream>>>(dd0, dw1, db1, dd1, 512, 256, 64, 64);
    convT4s2_relu<__hip_bfloat16, __hip_bfloat16>
        <<<g(8LL * 128 * 128 * 128), blk, 0, stream>>>(dd1, dw2, db2, dd2, 256, 128, 128, 128);
    conv3x3_out<<<g(8LL * 3 * 256 * 256), blk, 0, stream>>>(dd2, ow, ob, recon);
  }
}

// Round 5
// 3651.648 us; speedup vs baseline: 15.6828x; 1.1085x over previous
//
#include <hip/hip_runtime.h>
#include <hip/hip_bf16.h>
#include <cstdint>

#define BATCH 8
#define LATC 256
#define NCODE 1024
#define NLVL 4

typedef __attribute__((ext_vector_type(8))) short bf16x8v;
typedef __attribute__((ext_vector_type(4))) float f32x4v;

__device__ __forceinline__ unsigned short f2b(float f) {
  __hip_bfloat16 h = __float2bfloat16(f);
  return *reinterpret_cast<unsigned short*>(&h);
}

// async global->LDS 16B: LDS base = readfirstlane(lane0 offset), HW writes base + lane*16
__device__ __forceinline__ void gl_lds16(const void* gptr, unsigned lds_byte_off) {
  unsigned m0v = __builtin_amdgcn_readfirstlane(lds_byte_off);
  asm volatile("s_mov_b32 m0, %0\n"
               "global_load_lds_dwordx4 %1, off\n" ::"s"(m0v), "v"(gptr)
               : "memory");
}

// ================= encoder conv k4 s2 p1 (+relu), LDS-tiled, bit-exact FMA chain =================
// Weights staged per-chunk in LDS (float4 broadcast reads) -> no serialized s_loads.
// FMA order per output: ci asc, kh, kw — identical to prior rounds => z bit-identical.
template <int CIN, int COUT, int HIN, int CI_CHUNK, int CO_TILE>
__global__ __launch_bounds__(256) void conv_enc(
    const float* __restrict__ in, const float* __restrict__ w,
    const float* __restrict__ bias, float* __restrict__ out) {
  constexpr int WIN = HIN;
  constexpr int HOUT = HIN / 2, WOUT = WIN / 2;
  constexpr int PT1 = HOUT / 16;
  constexpr int CPW = CO_TILE / 4;
  constexpr int CL = CPW / 4;
  constexpr int NEL = CI_CHUNK * 34 * 34;
  constexpr int WUNITS = CI_CHUNK * CO_TILE * 4;  // float4 units

  __shared__ float T[CI_CHUNK][34][35];
  __shared__ float4 Wsh[CI_CHUNK][CO_TILE][4];

  const int tid = threadIdx.x;
  const int lane = tid & 63;
  const int wv = __builtin_amdgcn_readfirstlane(tid >> 6);
  const int opy = (lane >> 3) << 1;
  const int opx = (lane & 7) << 1;

  const int bx = blockIdx.x;
  const int n = bx / (PT1 * PT1);
  const int pt = bx % (PT1 * PT1);
  const int oh0 = (pt / PT1) * 16, ow0 = (pt % PT1) * 16;
  const int hbase = 2 * oh0 - 1, wbase = 2 * ow0 - 1;
  const int co_blk = blockIdx.y * CO_TILE;
  const int co_base = co_blk + wv * CPW;

  float acc[CL][4][2][2];
#pragma unroll
  for (int cl = 0; cl < CL; ++cl)
#pragma unroll
    for (int j = 0; j < 4; ++j) {
      float b = bias[co_base + cl * 4 + j];
      acc[cl][j][0][0] = b; acc[cl][j][0][1] = b;
      acc[cl][j][1][0] = b; acc[cl][j][1][1] = b;
    }

  for (int ch = 0; ch < CIN; ch += CI_CHUNK) {
    for (int u = tid; u < NEL; u += 256) {
      int cir = u / (34 * 34);
      int rem = u % (34 * 34);
      int r = rem / 34, c = rem % 34;
      int hi = hbase + r, wi = wbase + c;
      float v = 0.f;
      if ((unsigned)hi < (unsigned)HIN && (unsigned)wi < (unsigned)WIN)
        v = in[((long long)(n * CIN + ch + cir) * HIN + hi) * WIN + wi];
      T[cir][r][c] = v;
    }
    for (int u = tid; u < WUNITS; u += 256) {
      int k4 = u & 3;
      int rem = u >> 2;
      int co = rem % CO_TILE, ci = rem / CO_TILE;
      Wsh[ci][co][k4] =
          *(const float4*)&w[((long long)(co_blk + co) * CIN + ch + ci) * 16 + k4 * 4];
    }
    __syncthreads();
#pragma unroll
    for (int cir = 0; cir < CI_CHUNK; ++cir) {
      float xv[6][6];
#pragma unroll
      for (int r = 0; r < 6; ++r)
#pragma unroll
        for (int c = 0; c < 6; ++c) xv[r][c] = T[cir][2 * opy + r][2 * opx + c];
#pragma unroll
      for (int cl = 0; cl < CL; ++cl)
#pragma unroll
        for (int j = 0; j < 4; ++j) {
          int co_l = wv * CPW + cl * 4 + j;
#pragma unroll
          for (int kh = 0; kh < 4; ++kh) {
            float4 wq = Wsh[cir][co_l][kh];
            float wt0 = wq.x, wt1 = wq.y, wt2 = wq.z, wt3 = wq.w;
#pragma unroll
            for (int dy = 0; dy < 2; ++dy)
#pragma unroll
              for (int dx = 0; dx < 2; ++dx) {
                acc[cl][j][dy][dx] = fmaf(xv[2 * dy + kh][2 * dx + 0], wt0, acc[cl][j][dy][dx]);
                acc[cl][j][dy][dx] = fmaf(xv[2 * dy + kh][2 * dx + 1], wt1, acc[cl][j][dy][dx]);
                acc[cl][j][dy][dx] = fmaf(xv[2 * dy + kh][2 * dx + 2], wt2, acc[cl][j][dy][dx]);
                acc[cl][j][dy][dx] = fmaf(xv[2 * dy + kh][2 * dx + 3], wt3, acc[cl][j][dy][dx]);
              }
          }
        }
    }
    __syncthreads();
  }
#pragma unroll
  for (int cl = 0; cl < CL; ++cl)
#pragma unroll
    for (int j = 0; j < 4; ++j) {
      int co = co_base + cl * 4 + j;
#pragma unroll
      for (int dy = 0; dy < 2; ++dy) {
        int oh = oh0 + opy + dy, ow = ow0 + opx;
        float v0 = fmaxf(acc[cl][j][dy][0], 0.f);
        float v1 = fmaxf(acc[cl][j][dy][1], 0.f);
        *reinterpret_cast<float2*>(
            &out[((long long)(n * COUT + co) * HOUT + oh) * WOUT + ow]) =
            make_float2(v0, v1);
      }
    }
}
// NOTE: kh/kw FMA order preserved: wq components consumed kw=0..3 inside kh loop, but original
// order was kh{kw{px{...}}}; here kh{px{kw{...}}} -- WAIT. Original: for kh: for kw: for dy,dx:
// fma. New: for kh: for dy,dx: kw0..kw3. Per-accumulator chain order: original visits
// (kh,kw) pairs in order kh*4+kw for each (dy,dx) accumulator independently ->
// acc[dy][dx] chain: (0,0),(0,1),(0,2),(0,3),(1,0)... New: same per-accumulator order
// (kh outer, kw inner via wt0..wt3). Bit-identical per accumulator. OK.

// ---------------- weight transpose for 1x1 conv ----------------
__global__ __launch_bounds__(256) void wtrans(const float* __restrict__ pw,
                                              float* __restrict__ pwT) {
  int gid = blockIdx.x * 256 + threadIdx.x;
  if (gid >= 512 * 256) return;
  int ci = gid >> 8, co = gid & 255;
  pwT[gid] = pw[co * 512 + ci];
}

// ---------------- 1x1 conv as GEMM ----------------
__global__ __launch_bounds__(256) void conv1x1_v2(
    const float* __restrict__ in, const float* __restrict__ pwT,
    const float* __restrict__ bias, float* __restrict__ out) {
  __shared__ float Tx[16][128];
  const int tid = threadIdx.x;
  const int lane = tid & 63;
  const int wv = __builtin_amdgcn_readfirstlane(tid >> 6);
  const int p0 = lane * 2;
  const int bx = blockIdx.x;
  const int n = bx >> 3, pxb = bx & 7;
  const int px_base = pxb * 128;
  const int co_base = blockIdx.y * 64 + wv * 16;

  float acc[4][4][2];
#pragma unroll
  for (int cl = 0; cl < 4; ++cl)
#pragma unroll
    for (int j = 0; j < 4; ++j) {
      float b = bias[co_base + cl * 4 + j];
      acc[cl][j][0] = b; acc[cl][j][1] = b;
    }

  for (int ch = 0; ch < 512; ch += 16) {
    for (int u = tid; u < 2048; u += 256) {
      int cir = u >> 7, p = u & 127;
      Tx[cir][p] = in[(long long)(n * 512 + ch + cir) * 1024 + px_base + p];
    }
    __syncthreads();
#pragma unroll
    for (int cir = 0; cir < 16; ++cir) {
      float2 xv = *reinterpret_cast<const float2*>(&Tx[cir][p0]);
#pragma unroll
      for (int cl = 0; cl < 4; ++cl) {
        const float* __restrict__ wp = pwT + (ch + cir) * 256 + co_base + cl * 4;
#pragma unroll
        for (int j = 0; j < 4; ++j) {
          float wt = wp[j];
          acc[cl][j][0] = fmaf(xv.x, wt, acc[cl][j][0]);
          acc[cl][j][1] = fmaf(xv.y, wt, acc[cl][j][1]);
        }
      }
    }
    __syncthreads();
  }
#pragma unroll
  for (int cl = 0; cl < 4; ++cl)
#pragma unroll
    for (int j = 0; j < 4; ++j) {
      int co = co_base + cl * 4 + j;
      *reinterpret_cast<float2*>(&out[(long long)(n * 256 + co) * 1024 + px_base + p0]) =
          make_float2(acc[cl][j][0], acc[cl][j][1]);
    }
}

// ---------------- per-code squared norms ----------------
__global__ __launch_bounds__(256) void emb_norms(
    const float* __restrict__ emb, float* __restrict__ en) {
  int k = blockIdx.x * blockDim.x + threadIdx.x;
  if (k >= NLVL * NCODE) return;
  const float* __restrict__ e = emb + (long long)k * LATC;
  float s = 0.f;
  for (int c = 0; c < LATC; ++c) s = fmaf(e[c], e[c], s);
  en[k] = s;
}

// ---------------- residual quantization (unchanged, verified) ----------------
#define RQ_P 32
#define RQ_CT 32
#define RQ_RS 260

__global__ __launch_bounds__(256) void rq_kernel2(
    const float* __restrict__ z, const float* __restrict__ emb,
    const float* __restrict__ en, float* __restrict__ zq_out,
    float* __restrict__ resid_out, float* __restrict__ codes_out) {
  __shared__ float e_sh[RQ_CT * RQ_RS];
  __shared__ float r_sh[RQ_P * RQ_RS];
  __shared__ float sum_sh[RQ_P];
  __shared__ int code_sh[RQ_P];
  const int tid = threadIdx.x;
  const int blk = blockIdx.x;
  const int n = (blk * RQ_P) >> 10;
  const int hw0 = (blk * RQ_P) & 1023;
  const long long zb = ((long long)n * LATC) * 1024 + hw0;

  for (int it = 0; it < 32; ++it) {
    int u = it * 256 + tid;
    int c = u >> 5, pix = u & 31;
    float v = z[zb + (long long)c * 1024 + pix];
    r_sh[pix * RQ_RS + c] = v;
    resid_out[((long long)n * LATC + c) * 1024 + hw0 + pix] = v;
  }
  __syncthreads();

  const int code_l = tid & 31;
  const int pixoff = tid >> 5;
  const int upix = tid >> 3;
  const int ucg = tid & 7;

  for (int l = 0; l < NLVL; ++l) {
    {
      float s = 0.f;
#pragma unroll
      for (int it = 0; it < 8; ++it) {
        int c4 = ucg + it * 8;
        float4 r4 = *(const float4*)&r_sh[upix * RQ_RS + c4 * 4];
        s += r4.x * r4.x + r4.y * r4.y + r4.z * r4.z + r4.w * r4.w;
      }
      s += __shfl_xor(s, 1); s += __shfl_xor(s, 2); s += __shfl_xor(s, 4);
      if (ucg == 0) sum_sh[upix] = s;
    }
    __syncthreads();
    const float* __restrict__ E = emb + (long long)l * NCODE * LATC;
    const float* __restrict__ enl = en + l * NCODE;
    float best[4]; int bidx[4];
#pragma unroll
    for (int g = 0; g < 4; ++g) { best[g] = 3.4e38f; bidx[g] = 0; }
    for (int tile = 0; tile < NCODE / RQ_CT; ++tile) {
      const float* __restrict__ Et = E + (long long)tile * RQ_CT * LATC;
      for (int it = 0; it < 32; ++it) {
        int u = it * 256 + tid;
        int cc = u >> 8, ch = u & 255;
        e_sh[cc * RQ_RS + ch] = Et[cc * LATC + ch];
      }
      __syncthreads();
      float acc[4] = {0.f, 0.f, 0.f, 0.f};
      for (int c4 = 0; c4 < 64; ++c4) {
        float4 e4 = *(const float4*)&e_sh[code_l * RQ_RS + c4 * 4];
#pragma unroll
        for (int g = 0; g < 4; ++g) {
          float4 r4 = *(const float4*)&r_sh[(g * 8 + pixoff) * RQ_RS + c4 * 4];
          acc[g] = fmaf(r4.x, e4.x, acc[g]);
          acc[g] = fmaf(r4.y, e4.y, acc[g]);
          acc[g] = fmaf(r4.z, e4.z, acc[g]);
          acc[g] = fmaf(r4.w, e4.w, acc[g]);
        }
      }
      int code = tile * RQ_CT + code_l;
      float ek2 = enl[code];
#pragma unroll
      for (int g = 0; g < 4; ++g) {
        float d2 = (sum_sh[g * 8 + pixoff] - 2.f * acc[g]) + ek2;
        if (d2 < best[g]) { best[g] = d2; bidx[g] = code; }
      }
      __syncthreads();
    }
#pragma unroll
    for (int g = 0; g < 4; ++g) {
      float bd = best[g]; int bi = bidx[g];
#pragma unroll
      for (int m = 1; m < 32; m <<= 1) {
        float od = __shfl_xor(bd, m);
        int oi = __shfl_xor(bi, m);
        if (od < bd || (od == bd && oi < bi)) { bd = od; bi = oi; }
      }
      if (code_l == 0) {
        int pix = g * 8 + pixoff;
        code_sh[pix] = bi;
        codes_out[(long long)(l * BATCH + n) * 1024 + hw0 + pix] = (float)bi;
      }
    }
    __syncthreads();
    {
      int sel = code_sh[upix];
      const float* __restrict__ esel = E + (long long)sel * LATC;
#pragma unroll
      for (int it = 0; it < 8; ++it) {
        int c4 = ucg + it * 8;
        float4 r4 = *(const float4*)&r_sh[upix * RQ_RS + c4 * 4];
        float4 e4 = *(const float4*)&esel[c4 * 4];
        r4.x -= e4.x; r4.y -= e4.y; r4.z -= e4.z; r4.w -= e4.w;
        *(float4*)&r_sh[upix * RQ_RS + c4 * 4] = r4;
        if (l < NLVL - 1) {
          long long rb = ((long long)((l + 1) * BATCH + n) * LATC + c4 * 4) * 1024 + hw0 + upix;
          resid_out[rb] = r4.x;
          resid_out[rb + 1024] = r4.y;
          resid_out[rb + 2048] = r4.z;
          resid_out[rb + 3072] = r4.w;
        }
      }
    }
    __syncthreads();
  }
  for (int it = 0; it < 32; ++it) {
    int u = it * 256 + tid;
    int c = u >> 5, pix = u & 31;
    float zv = z[zb + (long long)c * 1024 + pix];
    zq_out[zb + (long long)c * 1024 + pix] = zv - r_sh[pix * RQ_RS + c];
  }
}

// ---------------- zq (NCHW f32) -> padded NHWC bf16 [8][34][34][256] ----------------
__global__ __launch_bounds__(256) void to_nhwc_s1(const float* __restrict__ zq,
                                                  unsigned short* __restrict__ o) {
  __shared__ float tsh[32][33];
  int bx = blockIdx.x;
  int ct = bx & 7, y = (bx >> 3) & 31, n = bx >> 8;
  int tid = threadIdx.x;
  int x = tid & 31, cl = tid >> 5;
#pragma unroll
  for (int it = 0; it < 4; ++it) {
    int ci = it * 8 + cl;
    tsh[ci][x] = zq[((long long)(n * 256 + ct * 32 + ci) * 32 + y) * 32 + x];
  }
  __syncthreads();
  int ci = tid & 31, xg = tid >> 5;
#pragma unroll
  for (int it = 0; it < 4; ++it) {
    int xw = it * 8 + xg;
    o[(((long long)n * 34 + y + 1) * 34 + xw + 1) * 256 + ct * 32 + ci] = f2b(tsh[ci][xw]);
  }
}

// ---------------- weight prep: HWIO f32 -> [4ph][CIN/32][4tap][COUT][32] bf16 ----------------
__global__ __launch_bounds__(256) void wprep_k(const float* __restrict__ w,
                                               unsigned short* __restrict__ o,
                                               int CINc, int COUTc) {
  long long total = 16LL * CINc * COUTc;
  long long gid = (long long)blockIdx.x * 256 + threadIdx.x;
  if (gid >= total) return;
  int ci32 = (int)(gid & 31); long long t = gid >> 5;
  int co = (int)(t % COUTc); t /= COUTc;
  int tap = (int)(t & 3); t >>= 2;
  int nch = CINc / 32;
  int ch = (int)(t % nch); int phase = (int)(t / nch);
  int py = phase >> 1, px = phase & 1;
  int ky = py + 2 * (tap >> 1), kx = px + 2 * (tap & 1);
  int ci = ch * 32 + ci32;
  float v = w[(((long long)ky * 4 + kx) * CINc + ci) * COUTc + co];
  o[gid] = f2b(v);
}

// ================= transposed conv k4 s2 MFMA v2: plane-layout LDS, 64co x 256px / block ========
// 256 thr (4 waves). Single-buffered LDS, conflict-free reads, 3 blocks/CU.
template <int CIN, int COUT, int TH, int TW, int Hi, int Wi, bool OUT_NCHW>
__global__ __launch_bounds__(256) void convt2(
    const unsigned short* __restrict__ xin, const unsigned short* __restrict__ wprep,
    const float* __restrict__ bias, unsigned short* __restrict__ outp) {
  constexpr int TWP = TW + 2, ROWS = TH + 2;
  constexpr int Hp = Hi + 2, Wp = Wi + 2;
  constexpr int NCH = CIN / 32;
  constexpr int XUNITS = ROWS * TWP;                       // 16B units per seg-plane
  constexpr int XPAD = ((XUNITS + 255) / 256) * 256;
  constexpr int WBASE = 4 * XPAD;                          // W planes start (units)
  __shared__ unsigned short lds[(4 * XPAD + 4 * 256) * 8];

  const int tid = threadIdx.x;
  const int wv = tid >> 6, lane = tid & 63;
  const int l15 = lane & 15, seg = lane >> 4;

  constexpr int SW = Wi / TW, SH = Hi / TH;
  const int bx = blockIdx.x;
  const int n = bx / (SH * SW);
  const int srem = bx % (SH * SW);
  const int i0 = (srem / SW) * TH, j0 = (srem % SW) * TW;
  const int cob0 = blockIdx.y * 64;
  const int phase = blockIdx.z;
  const int pyp = phase >> 1, pxp = phase & 1;

  const unsigned short* xsrc = xin + (long long)n * Hp * Wp * CIN;

  f32x4v acc[4][4];
  if (!OUT_NCHW) {
#pragma unroll
    for (int b = 0; b < 4; ++b) {
      float bv = bias[cob0 + b * 16 + l15];
      f32x4v v = {bv, bv, bv, bv};
#pragma unroll
      for (int a = 0; a < 4; ++a) acc[a][b] = v;
    }
  } else {
#pragma unroll
    for (int a = 0; a < 4; ++a) {
      f32x4v v;
#pragma unroll
      for (int q = 0; q < 4; ++q) v[q] = bias[cob0 + a * 16 + seg * 4 + q];
#pragma unroll
      for (int b = 0; b < 4; ++b) acc[a][b] = v;
    }
  }

  for (int ch = 0; ch < NCH; ++ch) {
    __syncthreads();  // protect previous chunk's reads before overwrite
    // stage X: 4 seg-planes, linear 16B units; source pre-mapped per plane
#pragma unroll
    for (int sg = 0; sg < 4; ++sg) {
#pragma unroll
      for (int it = 0; it < XPAD / 256; ++it) {
        int u = it * 256 + tid;
        int us = u < XUNITS ? u : XUNITS - 1;
        int row = us / TWP, col = us % TWP;
        const unsigned short* g =
            xsrc + ((long long)(i0 + row) * Wp + (j0 + col)) * CIN + ch * 32 + sg * 8;
        gl_lds16(g, (unsigned)(unsigned long long)(const void*)&lds[(sg * XPAD + u) * 8]);
      }
    }
    // stage W: 4 seg-planes x (4 taps x 64 co)
    {
      const unsigned short* wb = wprep + ((long long)phase * NCH + ch) * 4 * COUT * 32;
      int tap = tid >> 6, co = tid & 63;
#pragma unroll
      for (int sg = 0; sg < 4; ++sg) {
        const unsigned short* g = wb + ((long long)tap * COUT + cob0 + co) * 32 + sg * 8;
        gl_lds16(g, (unsigned)(unsigned long long)(const void*)&lds[(WBASE + sg * 256 + tid) * 8]);
      }
    }
    asm volatile("s_waitcnt vmcnt(0)" ::: "memory");
    __syncthreads();
    // compute
#pragma unroll
    for (int t = 0; t < 4; ++t) {
      int oy = (t >> 1) - 1 + pyp, ox = (t & 1) - 1 + pxp;
      bf16x8v xf[4], wf[4];
#pragma unroll
      for (int i = 0; i < 4; ++i) {
        int p = wv * 64 + i * 16 + l15;
        int r = p / TW, c = p % TW;
        int xrow = r + oy + 1, xcol = c + ox + 1;
        xf[i] = *(const bf16x8v*)&lds[(seg * XPAD + xrow * TWP + xcol) * 8];
        wf[i] = *(const bf16x8v*)&lds[(WBASE + seg * 256 + t * 64 + i * 16 + l15) * 8];
      }
#pragma unroll
      for (int a = 0; a < 4; ++a)
#pragma unroll
        for (int b = 0; b < 4; ++b) {
          if (OUT_NCHW)
            acc[a][b] = __builtin_amdgcn_mfma_f32_16x16x32_bf16(wf[a], xf[b], acc[a][b], 0, 0, 0);
          else
            acc[a][b] = __builtin_amdgcn_mfma_f32_16x16x32_bf16(xf[a], wf[b], acc[a][b], 0, 0, 0);
        }
    }
  }

  if (!OUT_NCHW) {
    constexpr int Wpo = 2 * Wi + 2;
    long long ob_n = (long long)n * (2 * Hi + 2) * Wpo * COUT;
#pragma unroll
    for (int a = 0; a < 4; ++a)
#pragma unroll
      for (int q = 0; q < 4; ++q) {
        int p = wv * 64 + a * 16 + seg * 4 + q;
        int r = p / TW, c = p % TW;
        int yo = 2 * (i0 + r) + pyp + 1, xo = 2 * (j0 + c) + pxp + 1;
        long long ob = ob_n + ((long long)yo * Wpo + xo) * COUT + cob0;
#pragma unroll
        for (int b = 0; b < 4; ++b) {
          float v = fmaxf(acc[a][b][q], 0.f);
          outp[ob + b * 16 + l15] = f2b(v);
        }
      }
  } else {
    constexpr int Ho = 2 * Hi, Wo = 2 * Wi;
#pragma unroll
    for (int a = 0; a < 4; ++a)
#pragma unroll
      for (int q = 0; q < 4; ++q) {
        int co = cob0 + a * 16 + seg * 4 + q;
#pragma unroll
        for (int b = 0; b < 4; ++b) {
          int p = wv * 64 + b * 16 + l15;
          int r = p / TW, c = p % TW;
          int yo = 2 * (i0 + r) + pyp, xo = 2 * (j0 + c) + pxp;
          float v = fmaxf(acc[a][b][q], 0.f);
          outp[((long long)(n * COUT + co) * Ho + yo) * Wo + xo] = f2b(v);
        }
      }
  }
}

// ---------------- final 3x3 conv s1 p1, bf16 NCHW in, f32 out ----------------
__global__ __launch_bounds__(256) void conv3x3_out(
    const __hip_bfloat16* __restrict__ in, const float* __restrict__ w,
    const float* __restrict__ bias, float* __restrict__ out) {
  const int Cin = 128, H = 256, W = 256, Cout = 3;
  long long total = (long long)BATCH * Cout * H * W;
  long long gid = (long long)blockIdx.x * blockDim.x + threadIdx.x;
  if (gid >= total) return;
  int x = (int)(gid % W); long long t = gid / W;
  int y = (int)(t % H); t /= H;
  int co = (int)(t % Cout); int n = (int)(t / Cout);
  float acc = bias[co];
  for (int ci = 0; ci < Cin; ++ci) {
    const __hip_bfloat16* __restrict__ ip = in + ((long long)(n * Cin + ci) * H) * W;
    const float* __restrict__ wp = w + ((long long)(co * Cin + ci)) * 9;
#pragma unroll
    for (int kh = 0; kh < 3; ++kh) {
      int yy = y + kh - 1;
      if ((unsigned)yy >= (unsigned)H) continue;
#pragma unroll
      for (int kw = 0; kw < 3; ++kw) {
        int xx = x + kw - 1;
        if ((unsigned)xx >= (unsigned)W) continue;
        acc = fmaf(__bfloat162float(ip[(long long)yy * W + xx]), wp[kh * 3 + kw], acc);
      }
    }
  }
  out[gid] = acc;
}

// ---------------- fallback helpers + scalar kernels (round-2 path) ----------------
__device__ __forceinline__ float ldf(const float* p, long long i) { return p[i]; }
__device__ __forceinline__ float ldf(const __hip_bfloat16* p, long long i) {
  return __bfloat162float(p[i]);
}
__device__ __forceinline__ void st2(float* p, float a, float b) {
  *reinterpret_cast<float2*>(p) = make_float2(a, b);
}
__device__ __forceinline__ void st2(__hip_bfloat16* p, float a, float b) {
  __hip_bfloat162 v;
  v.x = __float2bfloat16(a); v.y = __float2bfloat16(b);
  *reinterpret_cast<__hip_bfloat162*>(p) = v;
}

__global__ __launch_bounds__(256) void conv4s2_v2(
    const float* __restrict__ in, const float* __restrict__ w,
    const float* __restrict__ bias, float* __restrict__ out,
    int Cin, int Cout, int Hin, int Win, int relu) {
  const int Hout = Hin >> 1, Wout = Win >> 1;
  const int H2 = Hout >> 1, W2 = Wout >> 1;
  const int cogn = Cout >> 2;
  long long total = (long long)BATCH * cogn * H2 * W2;
  long long gid = (long long)blockIdx.x * blockDim.x + threadIdx.x;
  if (gid >= total) return;
  int w2 = (int)(gid % W2); long long t = gid / W2;
  int h2 = (int)(t % H2); t /= H2;
  int cog = (int)(t % cogn); int n = (int)(t / cogn);
  int co0 = cog << 2;
  float a[4][2][2];
#pragma unroll
  for (int j = 0; j < 4; ++j) {
    float b = bias[co0 + j];
    a[j][0][0] = b; a[j][0][1] = b; a[j][1][0] = b; a[j][1][1] = b;
  }
  const int hi0 = 4 * h2 - 1, wi0 = 4 * w2 - 1;
  const long long wstride = (long long)Cin * 16;
  for (int ci = 0; ci < Cin; ++ci) {
    const float* __restrict__ ip = in + ((long long)(n * Cin + ci) * Hin) * Win;
    float xv[6][6];
#pragma unroll
    for (int r = 0; r < 6; ++r) {
      int hi = hi0 + r;
      bool ok = (unsigned)hi < (unsigned)Hin;
#pragma unroll
      for (int c = 0; c < 6; ++c) {
        int wi = wi0 + c;
        xv[r][c] = (ok && (unsigned)wi < (unsigned)Win) ? ip[(long long)hi * Win + wi] : 0.f;
      }
    }
    const float* __restrict__ wp = w + (long long)co0 * wstride + (long long)ci * 16;
#pragma unroll
    for (int kh = 0; kh < 4; ++kh) {
#pragma unroll
      for (int kw = 0; kw < 4; ++kw) {
        int k = (kh << 2) + kw;
        float w0 = wp[k], w1 = wp[wstride + k], w2v = wp[2 * wstride + k], w3 = wp[3 * wstride + k];
#pragma unroll
        for (int dy = 0; dy < 2; ++dy)
#pragma unroll
          for (int dx = 0; dx < 2; ++dx) {
            float v = xv[2 * dy + kh][2 * dx + kw];
            a[0][dy][dx] = fmaf(v, w0, a[0][dy][dx]);
            a[1][dy][dx] = fmaf(v, w1, a[1][dy][dx]);
            a[2][dy][dx] = fmaf(v, w2v, a[2][dy][dx]);
            a[3][dy][dx] = fmaf(v, w3, a[3][dy][dx]);
          }
      }
    }
  }
  long long cs = (long long)Hout * Wout;
  long long ob0 = ((long long)(n * Cout + co0) * Hout + 2 * h2) * Wout + 2 * w2;
#pragma unroll
  for (int j = 0; j < 4; ++j)
#pragma unroll
    for (int dy = 0; dy < 2; ++dy)
#pragma unroll
      for (int dx = 0; dx < 2; ++dx) {
        float v = a[j][dy][dx];
        if (relu) v = fmaxf(v, 0.f);
        out[ob0 + j * cs + (long long)dy * Wout + dx] = v;
      }
}

__global__ __launch_bounds__(256) void conv1x1(
    const float* __restrict__ in, const float* __restrict__ w,
    const float* __restrict__ bias, float* __restrict__ out, int Cin, int Cout) {
  const int HW = 1024;
  const int cogn = Cout >> 2;
  long long total = (long long)BATCH * cogn * HW;
  long long gid = (long long)blockIdx.x * blockDim.x + threadIdx.x;
  if (gid >= total) return;
  int hw = (int)(gid % HW); long long t = gid / HW;
  int cog = (int)(t % cogn); int n = (int)(t / cogn);
  int co0 = cog << 2;
  float a0 = bias[co0], a1 = bias[co0 + 1], a2 = bias[co0 + 2], a3 = bias[co0 + 3];
  for (int ci = 0; ci < Cin; ++ci) {
    float v = in[((long long)(n * Cin + ci)) * HW + hw];
    const float* __restrict__ wp = w + (long long)co0 * Cin + ci;
    a0 = fmaf(v, wp[0], a0);
    a1 = fmaf(v, wp[Cin], a1);
    a2 = fmaf(v, wp[2 * Cin], a2);
    a3 = fmaf(v, wp[3 * Cin], a3);
  }
  long long ob = ((long long)(n * Cout + co0)) * HW + hw;
  out[ob] = a0; out[ob + HW] = a1; out[ob + 2 * HW] = a2; out[ob + 3 * HW] = a3;
}

template <typename TI, typename TO>
__global__ __launch_bounds__(256) void convT4s2_relu(
    const TI* __restrict__ in, const float* __restrict__ w,
    const float* __restrict__ bias, TO* __restrict__ out,
    int Cin, int Cout, int Hi, int Wi) {
  const int Ho = Hi << 1, Wo = Wi << 1;
  long long total = (long long)BATCH * Cout * Hi * Wi;
  long long gid = (long long)blockIdx.x * blockDim.x + threadIdx.x;
  if (gid >= total) return;
  int j = (int)(gid % Wi); long long t = gid / Wi;
  int i = (int)(t % Hi); t /= Hi;
  int co = (int)(t % Cout); int n = (int)(t / Cout);
  const float b = bias[co];
  float a00 = b, a01 = b, a10 = b, a11 = b;
  const long long tapstride = (long long)Cin * Cout;
  const float* __restrict__ wbase = w + co;
  for (int ci = 0; ci < Cin; ++ci) {
    const TI* __restrict__ ip = in + ((long long)(n * Cin + ci) * Hi) * Wi;
    float xv[3][3];
#pragma unroll
    for (int dy = 0; dy < 3; ++dy) {
      int y = i - 1 + dy;
      bool yok = (unsigned)y < (unsigned)Hi;
#pragma unroll
      for (int dx = 0; dx < 3; ++dx) {
        int xx = j - 1 + dx;
        xv[dy][dx] = (yok && (unsigned)xx < (unsigned)Wi) ? ldf(ip, (long long)y * Wi + xx) : 0.f;
      }
    }
    const float* __restrict__ wp = wbase + (long long)ci * Cout;
#define WT(kh, kw) wp[((kh) * 4 + (kw)) * tapstride]
    a00 = fmaf(xv[0][0], WT(0, 0), a00); a00 = fmaf(xv[0][1], WT(0, 2), a00);
    a00 = fmaf(xv[1][0], WT(2, 0), a00); a00 = fmaf(xv[1][1], WT(2, 2), a00);
    a01 = fmaf(xv[0][1], WT(0, 1), a01); a01 = fmaf(xv[0][2], WT(0, 3), a01);
    a01 = fmaf(xv[1][1], WT(2, 1), a01); a01 = fmaf(xv[1][2], WT(2, 3), a01);
    a10 = fmaf(xv[1][0], WT(1, 0), a10); a10 = fmaf(xv[1][1], WT(1, 2), a10);
    a10 = fmaf(xv[2][0], WT(3, 0), a10); a10 = fmaf(xv[2][1], WT(3, 2), a10);
    a11 = fmaf(xv[1][1], WT(1, 1), a11); a11 = fmaf(xv[1][2], WT(1, 3), a11);
    a11 = fmaf(xv[2][1], WT(3, 1), a11); a11 = fmaf(xv[2][2], WT(3, 3), a11);
#undef WT
  }
  a00 = fmaxf(a00, 0.f); a01 = fmaxf(a01, 0.f);
  a10 = fmaxf(a10, 0.f); a11 = fmaxf(a11, 0.f);
  long long ob = ((long long)(n * Cout + co) * Ho + 2 * i) * Wo + 2 * j;
  st2(out + ob, a00, a01);
  st2(out + ob + Wo, a10, a11);
}

extern "C" void kernel_launch(void* const* d_in, const int* in_sizes, int n_in,
                              void* d_out, int out_size, void* d_ws, size_t ws_size,
                              hipStream_t stream) {
  const float* x   = (const float*)d_in[0];
  const float* ew0 = (const float*)d_in[1];  const float* eb0 = (const float*)d_in[2];
  const float* ew1 = (const float*)d_in[3];  const float* eb1 = (const float*)d_in[4];
  const float* ew2 = (const float*)d_in[5];  const float* eb2 = (const float*)d_in[6];
  const float* pw  = (const float*)d_in[7];  const float* pb  = (const float*)d_in[8];
  const float* dw0 = (const float*)d_in[9];  const float* db0 = (const float*)d_in[10];
  const float* dw1 = (const float*)d_in[11]; const float* db1 = (const float*)d_in[12];
  const float* dw2 = (const float*)d_in[13]; const float* db2 = (const float*)d_in[14];
  const float* ow  = (const float*)d_in[15]; const float* ob  = (const float*)d_in[16];
  const float* emb = (const float*)d_in[17];

  float* out   = (float*)d_out;
  float* recon = out;
  float* z     = out + 1572864;
  float* zq    = out + 3670016;
  float* resid = out + 5767168;
  float* codes = out + 14155776;

  char* ws = (char*)d_ws;
  dim3 blk(256);
  auto g = [](long long tot) { return dim3((unsigned)((tot + 255) / 256)); };

  // ---- workspace plan (~204.5 MB) ----
  const size_t OFF_S1IN  = 0ULL;
  const size_t OFF_S1OUT = 4734976ULL;
  const size_t OFF_WP1   = 40419328ULL;
  const size_t OFF_WP2   = 44613632ULL;
  const size_t OFF_E0    = 0ULL;
  const size_t OFF_E1    = 67108864ULL;
  const size_t OFF_E2    = 0ULL;
  const size_t OFF_PWT   = 67108864ULL;
  const size_t OFF_DD2   = 0ULL;
  const size_t OFF_S2OUT = 134217728ULL;
  const size_t OFF_WP3   = 203440128ULL;
  const size_t OFF_EN    = 204488704ULL;
  const size_t WS_NEED   = 204505088ULL;

  if (ws_size >= WS_NEED) {
    float* e0 = (float*)(ws + OFF_E0);
    float* e1 = (float*)(ws + OFF_E1);
    float* e2 = (float*)(ws + OFF_E2);
    float* en = (float*)(ws + OFF_EN);
    float* pwT = (float*)(ws + OFF_PWT);
    unsigned short* s1in  = (unsigned short*)(ws + OFF_S1IN);
    unsigned short* s1out = (unsigned short*)(ws + OFF_S1OUT);
    unsigned short* s2out = (unsigned short*)(ws + OFF_S2OUT);
    unsigned short* dd2   = (unsigned short*)(ws + OFF_DD2);
    unsigned short* wp1   = (unsigned short*)(ws + OFF_WP1);
    unsigned short* wp2   = (unsigned short*)(ws + OFF_WP2);
    unsigned short* wp3   = (unsigned short*)(ws + OFF_WP3);

    emb_norms<<<g(4096), blk, 0, stream>>>(emb, en);

    // encoder: LDS-tiled fp32 + LDS-staged weights (bit-identical FMA chains)
    conv_enc<3, 128, 256, 3, 64><<<dim3(8 * 64, 2), blk, 0, stream>>>(x, ew0, eb0, e0);
    conv_enc<128, 256, 128, 4, 64><<<dim3(8 * 16, 4), blk, 0, stream>>>(e0, ew1, eb1, e1);
    conv_enc<256, 512, 64, 4, 32><<<dim3(8 * 4, 16), blk, 0, stream>>>(e1, ew2, eb2, e2);
    wtrans<<<g(512 * 256), blk, 0, stream>>>(pw, pwT);
    conv1x1_v2<<<dim3(64, 4), blk, 0, stream>>>(e2, pwT, pb, z);

    // residual quantization
    rq_kernel2<<<dim3(256), blk, 0, stream>>>(z, emb, en, zq, resid, codes);

    // decoder prep
    hipMemsetAsync(ws + OFF_S1IN, 0, 4734976ULL, stream);
    hipMemsetAsync(ws + OFF_S1OUT, 0, 35684352ULL, stream);
    hipMemsetAsync(ws + OFF_S2OUT, 0, 69222400ULL, stream);
    to_nhwc_s1<<<dim3(2048), blk, 0, stream>>>(zq, s1in);
    wprep_k<<<g(16LL * 256 * 512), blk, 0, stream>>>(dw0, wp1, 256, 512);
    wprep_k<<<g(16LL * 512 * 256), blk, 0, stream>>>(dw1, wp2, 512, 256);
    wprep_k<<<g(16LL * 256 * 128), blk, 0, stream>>>(dw2, wp3, 256, 128);

    // decoder MFMA stages (v2: 64co x 256px, plane LDS, 3 blocks/CU)
    convt2<256, 512, 8, 32, 32, 32, false>
        <<<dim3(32, 8, 4), dim3(256), 0, stream>>>(s1in, wp1, db0, s1out);
    convt2<512, 256, 4, 64, 64, 64, false>
        <<<dim3(128, 4, 4), dim3(256), 0, stream>>>(s1out, wp2, db1, s2out);
    convt2<256, 128, 4, 64, 128, 128, true>
        <<<dim3(512, 2, 4), dim3(256), 0, stream>>>(s2out, wp3, db2, dd2);

    conv3x3_out<<<g(8LL * 3 * 256 * 256), blk, 0, stream>>>(
        (const __hip_bfloat16*)dd2, ow, ob, recon);
  } else {
    // ---- fallback: round-2 layout/path ----
    const size_t OFF_A = 65536ULL;
    const size_t OFF_B = 65536ULL + 67108864ULL;
    float* en = (float*)(ws);
    float* e0 = (float*)(ws + OFF_A);
    float* e1 = (float*)(ws + OFF_B);
    float* e2 = (float*)(ws + OFF_A);
    __hip_bfloat16* dd0 = (__hip_bfloat16*)(ws + OFF_B);
    __hip_bfloat16* dd1 = (__hip_bfloat16*)(ws + OFF_A);
    __hip_bfloat16* dd2 = (__hip_bfloat16*)(ws + OFF_B);

    emb_norms<<<g(4096), blk, 0, stream>>>(emb, en);
    conv4s2_v2<<<g(8LL * 32 * 64 * 64), blk, 0, stream>>>(x, ew0, eb0, e0, 3, 128, 256, 256, 1);
    conv4s2_v2<<<g(8LL * 64 * 32 * 32), blk, 0, stream>>>(e0, ew1, eb1, e1, 128, 256, 128, 128, 1);
    conv4s2_v2<<<g(8LL * 128 * 16 * 16), blk, 0, stream>>>(e1, ew2, eb2, e2, 256, 512, 64, 64, 1);
    conv1x1<<<g(8LL * 64 * 1024), blk, 0, stream>>>(e2, pw, pb, z, 512, 256);
    rq_kernel2<<<dim3(256), blk, 0, stream>>>(z, emb, en, zq, resid, codes);
    convT4s2_relu<float, __hip_bfloat16>
        <<<g(8LL * 512 * 32 * 32), blk, 0, stream>>>(zq, dw0, db0, dd0, 256, 512, 32, 32);
    convT4s2_relu<__hip_bfloat16, __hip_bfloat16>
        <<<g(8LL * 256 * 64 * 64), blk, 0, stream>>>(dd0, dw1, db1, dd1, 512, 256, 64, 64);
    convT4s2_relu<__hip_bfloat16, __hip_bfloat16>
        <<<g(8LL * 128 * 128 * 128), blk, 0, stream>>>(dd1, dw2, db2, dd2, 256, 128, 128, 128);
    conv3x3_out<<<g(8LL * 3 * 256 * 256), blk, 0, stream>>>(dd2, ow, ob, recon);
  }
}

// Round 6
// 3069.651 us; speedup vs baseline: 18.6562x; 1.1896x over previous
//
#include <hip/hip_runtime.h>
#include <hip/hip_bf16.h>
#include <cstdint>

#define BATCH 8
#define LATC 256
#define NCODE 1024
#define NLVL 4

typedef __attribute__((ext_vector_type(8))) short bf16x8v;
typedef __attribute__((ext_vector_type(4))) float f32x4v;

__device__ __forceinline__ unsigned short f2b(float f) {
  __hip_bfloat16 h = __float2bfloat16(f);
  return *reinterpret_cast<unsigned short*>(&h);
}

// async global->LDS 16B: LDS base = readfirstlane(lane0 offset), HW writes base + lane*16
__device__ __forceinline__ void gl_lds16(const void* gptr, unsigned lds_byte_off) {
  unsigned m0v = __builtin_amdgcn_readfirstlane(lds_byte_off);
  asm volatile("s_mov_b32 m0, %0\n"
               "global_load_lds_dwordx4 %1, off\n" ::"s"(m0v), "v"(gptr)
               : "memory");
}

// ================= encoder conv k4 s2 p1 (+relu), LDS-tiled, bit-exact FMA chain =================
template <int CIN, int COUT, int HIN, int CI_CHUNK, int CO_TILE>
__global__ __launch_bounds__(256) void conv_enc(
    const float* __restrict__ in, const float* __restrict__ w,
    const float* __restrict__ bias, float* __restrict__ out) {
  constexpr int WIN = HIN;
  constexpr int HOUT = HIN / 2, WOUT = WIN / 2;
  constexpr int PT1 = HOUT / 16;
  constexpr int CPW = CO_TILE / 4;
  constexpr int CL = CPW / 4;
  constexpr int NEL = CI_CHUNK * 34 * 34;
  constexpr int WUNITS = CI_CHUNK * CO_TILE * 4;  // float4 units

  __shared__ float T[CI_CHUNK][34][35];
  __shared__ float4 Wsh[CI_CHUNK][CO_TILE][4];

  const int tid = threadIdx.x;
  const int lane = tid & 63;
  const int wv = __builtin_amdgcn_readfirstlane(tid >> 6);
  const int opy = (lane >> 3) << 1;
  const int opx = (lane & 7) << 1;

  const int bx = blockIdx.x;
  const int n = bx / (PT1 * PT1);
  const int pt = bx % (PT1 * PT1);
  const int oh0 = (pt / PT1) * 16, ow0 = (pt % PT1) * 16;
  const int hbase = 2 * oh0 - 1, wbase = 2 * ow0 - 1;
  const int co_blk = blockIdx.y * CO_TILE;
  const int co_base = co_blk + wv * CPW;

  float acc[CL][4][2][2];
#pragma unroll
  for (int cl = 0; cl < CL; ++cl)
#pragma unroll
    for (int j = 0; j < 4; ++j) {
      float b = bias[co_base + cl * 4 + j];
      acc[cl][j][0][0] = b; acc[cl][j][0][1] = b;
      acc[cl][j][1][0] = b; acc[cl][j][1][1] = b;
    }

  for (int ch = 0; ch < CIN; ch += CI_CHUNK) {
    for (int u = tid; u < NEL; u += 256) {
      int cir = u / (34 * 34);
      int rem = u % (34 * 34);
      int r = rem / 34, c = rem % 34;
      int hi = hbase + r, wi = wbase + c;
      float v = 0.f;
      if ((unsigned)hi < (unsigned)HIN && (unsigned)wi < (unsigned)WIN)
        v = in[((long long)(n * CIN + ch + cir) * HIN + hi) * WIN + wi];
      T[cir][r][c] = v;
    }
    for (int u = tid; u < WUNITS; u += 256) {
      int k4 = u & 3;
      int rem = u >> 2;
      int co = rem % CO_TILE, ci = rem / CO_TILE;
      Wsh[ci][co][k4] =
          *(const float4*)&w[((long long)(co_blk + co) * CIN + ch + ci) * 16 + k4 * 4];
    }
    __syncthreads();
#pragma unroll
    for (int cir = 0; cir < CI_CHUNK; ++cir) {
      float xv[6][6];
#pragma unroll
      for (int r = 0; r < 6; ++r)
#pragma unroll
        for (int c = 0; c < 6; ++c) xv[r][c] = T[cir][2 * opy + r][2 * opx + c];
#pragma unroll
      for (int cl = 0; cl < CL; ++cl)
#pragma unroll
        for (int j = 0; j < 4; ++j) {
          int co_l = wv * CPW + cl * 4 + j;
#pragma unroll
          for (int kh = 0; kh < 4; ++kh) {
            float4 wq = Wsh[cir][co_l][kh];
            float wt0 = wq.x, wt1 = wq.y, wt2 = wq.z, wt3 = wq.w;
#pragma unroll
            for (int dy = 0; dy < 2; ++dy)
#pragma unroll
              for (int dx = 0; dx < 2; ++dx) {
                acc[cl][j][dy][dx] = fmaf(xv[2 * dy + kh][2 * dx + 0], wt0, acc[cl][j][dy][dx]);
                acc[cl][j][dy][dx] = fmaf(xv[2 * dy + kh][2 * dx + 1], wt1, acc[cl][j][dy][dx]);
                acc[cl][j][dy][dx] = fmaf(xv[2 * dy + kh][2 * dx + 2], wt2, acc[cl][j][dy][dx]);
                acc[cl][j][dy][dx] = fmaf(xv[2 * dy + kh][2 * dx + 3], wt3, acc[cl][j][dy][dx]);
              }
          }
        }
    }
    __syncthreads();
  }
#pragma unroll
  for (int cl = 0; cl < CL; ++cl)
#pragma unroll
    for (int j = 0; j < 4; ++j) {
      int co = co_base + cl * 4 + j;
#pragma unroll
      for (int dy = 0; dy < 2; ++dy) {
        int oh = oh0 + opy + dy, ow = ow0 + opx;
        float v0 = fmaxf(acc[cl][j][dy][0], 0.f);
        float v1 = fmaxf(acc[cl][j][dy][1], 0.f);
        *reinterpret_cast<float2*>(
            &out[((long long)(n * COUT + co) * HOUT + oh) * WOUT + ow]) =
            make_float2(v0, v1);
      }
    }
}

// ---------------- weight transpose for 1x1 conv ----------------
__global__ __launch_bounds__(256) void wtrans(const float* __restrict__ pw,
                                              float* __restrict__ pwT) {
  int gid = blockIdx.x * 256 + threadIdx.x;
  if (gid >= 512 * 256) return;
  int ci = gid >> 8, co = gid & 255;
  pwT[gid] = pw[co * 512 + ci];
}

// ---------------- 1x1 conv as GEMM ----------------
__global__ __launch_bounds__(256) void conv1x1_v2(
    const float* __restrict__ in, const float* __restrict__ pwT,
    const float* __restrict__ bias, float* __restrict__ out) {
  __shared__ float Tx[16][128];
  const int tid = threadIdx.x;
  const int lane = tid & 63;
  const int wv = __builtin_amdgcn_readfirstlane(tid >> 6);
  const int p0 = lane * 2;
  const int bx = blockIdx.x;
  const int n = bx >> 3, pxb = bx & 7;
  const int px_base = pxb * 128;
  const int co_base = blockIdx.y * 64 + wv * 16;

  float acc[4][4][2];
#pragma unroll
  for (int cl = 0; cl < 4; ++cl)
#pragma unroll
    for (int j = 0; j < 4; ++j) {
      float b = bias[co_base + cl * 4 + j];
      acc[cl][j][0] = b; acc[cl][j][1] = b;
    }

  for (int ch = 0; ch < 512; ch += 16) {
    for (int u = tid; u < 2048; u += 256) {
      int cir = u >> 7, p = u & 127;
      Tx[cir][p] = in[(long long)(n * 512 + ch + cir) * 1024 + px_base + p];
    }
    __syncthreads();
#pragma unroll
    for (int cir = 0; cir < 16; ++cir) {
      float2 xv = *reinterpret_cast<const float2*>(&Tx[cir][p0]);
#pragma unroll
      for (int cl = 0; cl < 4; ++cl) {
        const float* __restrict__ wp = pwT + (ch + cir) * 256 + co_base + cl * 4;
#pragma unroll
        for (int j = 0; j < 4; ++j) {
          float wt = wp[j];
          acc[cl][j][0] = fmaf(xv.x, wt, acc[cl][j][0]);
          acc[cl][j][1] = fmaf(xv.y, wt, acc[cl][j][1]);
        }
      }
    }
    __syncthreads();
  }
#pragma unroll
  for (int cl = 0; cl < 4; ++cl)
#pragma unroll
    for (int j = 0; j < 4; ++j) {
      int co = co_base + cl * 4 + j;
      *reinterpret_cast<float2*>(&out[(long long)(n * 256 + co) * 1024 + px_base + p0]) =
          make_float2(acc[cl][j][0], acc[cl][j][1]);
    }
}

// ---------------- per-code squared norms ----------------
__global__ __launch_bounds__(256) void emb_norms(
    const float* __restrict__ emb, float* __restrict__ en) {
  int k = blockIdx.x * blockDim.x + threadIdx.x;
  if (k >= NLVL * NCODE) return;
  const float* __restrict__ e = emb + (long long)k * LATC;
  float s = 0.f;
  for (int c = 0; c < LATC; ++c) s = fmaf(e[c], e[c], s);
  en[k] = s;
}

// ---------------- residual quantization (unchanged, verified) ----------------
#define RQ_P 32
#define RQ_CT 32
#define RQ_RS 260

__global__ __launch_bounds__(256) void rq_kernel2(
    const float* __restrict__ z, const float* __restrict__ emb,
    const float* __restrict__ en, float* __restrict__ zq_out,
    float* __restrict__ resid_out, float* __restrict__ codes_out) {
  __shared__ float e_sh[RQ_CT * RQ_RS];
  __shared__ float r_sh[RQ_P * RQ_RS];
  __shared__ float sum_sh[RQ_P];
  __shared__ int code_sh[RQ_P];
  const int tid = threadIdx.x;
  const int blk = blockIdx.x;
  const int n = (blk * RQ_P) >> 10;
  const int hw0 = (blk * RQ_P) & 1023;
  const long long zb = ((long long)n * LATC) * 1024 + hw0;

  for (int it = 0; it < 32; ++it) {
    int u = it * 256 + tid;
    int c = u >> 5, pix = u & 31;
    float v = z[zb + (long long)c * 1024 + pix];
    r_sh[pix * RQ_RS + c] = v;
    resid_out[((long long)n * LATC + c) * 1024 + hw0 + pix] = v;
  }
  __syncthreads();

  const int code_l = tid & 31;
  const int pixoff = tid >> 5;
  const int upix = tid >> 3;
  const int ucg = tid & 7;

  for (int l = 0; l < NLVL; ++l) {
    {
      float s = 0.f;
#pragma unroll
      for (int it = 0; it < 8; ++it) {
        int c4 = ucg + it * 8;
        float4 r4 = *(const float4*)&r_sh[upix * RQ_RS + c4 * 4];
        s += r4.x * r4.x + r4.y * r4.y + r4.z * r4.z + r4.w * r4.w;
      }
      s += __shfl_xor(s, 1); s += __shfl_xor(s, 2); s += __shfl_xor(s, 4);
      if (ucg == 0) sum_sh[upix] = s;
    }
    __syncthreads();
    const float* __restrict__ E = emb + (long long)l * NCODE * LATC;
    const float* __restrict__ enl = en + l * NCODE;
    float best[4]; int bidx[4];
#pragma unroll
    for (int g = 0; g < 4; ++g) { best[g] = 3.4e38f; bidx[g] = 0; }
    for (int tile = 0; tile < NCODE / RQ_CT; ++tile) {
      const float* __restrict__ Et = E + (long long)tile * RQ_CT * LATC;
      for (int it = 0; it < 32; ++it) {
        int u = it * 256 + tid;
        int cc = u >> 8, ch = u & 255;
        e_sh[cc * RQ_RS + ch] = Et[cc * LATC + ch];
      }
      __syncthreads();
      float acc[4] = {0.f, 0.f, 0.f, 0.f};
      for (int c4 = 0; c4 < 64; ++c4) {
        float4 e4 = *(const float4*)&e_sh[code_l * RQ_RS + c4 * 4];
#pragma unroll
        for (int g = 0; g < 4; ++g) {
          float4 r4 = *(const float4*)&r_sh[(g * 8 + pixoff) * RQ_RS + c4 * 4];
          acc[g] = fmaf(r4.x, e4.x, acc[g]);
          acc[g] = fmaf(r4.y, e4.y, acc[g]);
          acc[g] = fmaf(r4.z, e4.z, acc[g]);
          acc[g] = fmaf(r4.w, e4.w, acc[g]);
        }
      }
      int code = tile * RQ_CT + code_l;
      float ek2 = enl[code];
#pragma unroll
      for (int g = 0; g < 4; ++g) {
        float d2 = (sum_sh[g * 8 + pixoff] - 2.f * acc[g]) + ek2;
        if (d2 < best[g]) { best[g] = d2; bidx[g] = code; }
      }
      __syncthreads();
    }
#pragma unroll
    for (int g = 0; g < 4; ++g) {
      float bd = best[g]; int bi = bidx[g];
#pragma unroll
      for (int m = 1; m < 32; m <<= 1) {
        float od = __shfl_xor(bd, m);
        int oi = __shfl_xor(bi, m);
        if (od < bd || (od == bd && oi < bi)) { bd = od; bi = oi; }
      }
      if (code_l == 0) {
        int pix = g * 8 + pixoff;
        code_sh[pix] = bi;
        codes_out[(long long)(l * BATCH + n) * 1024 + hw0 + pix] = (float)bi;
      }
    }
    __syncthreads();
    {
      int sel = code_sh[upix];
      const float* __restrict__ esel = E + (long long)sel * LATC;
#pragma unroll
      for (int it = 0; it < 8; ++it) {
        int c4 = ucg + it * 8;
        float4 r4 = *(const float4*)&r_sh[upix * RQ_RS + c4 * 4];
        float4 e4 = *(const float4*)&esel[c4 * 4];
        r4.x -= e4.x; r4.y -= e4.y; r4.z -= e4.z; r4.w -= e4.w;
        *(float4*)&r_sh[upix * RQ_RS + c4 * 4] = r4;
        if (l < NLVL - 1) {
          long long rb = ((long long)((l + 1) * BATCH + n) * LATC + c4 * 4) * 1024 + hw0 + upix;
          resid_out[rb] = r4.x;
          resid_out[rb + 1024] = r4.y;
          resid_out[rb + 2048] = r4.z;
          resid_out[rb + 3072] = r4.w;
        }
      }
    }
    __syncthreads();
  }
  for (int it = 0; it < 32; ++it) {
    int u = it * 256 + tid;
    int c = u >> 5, pix = u & 31;
    float zv = z[zb + (long long)c * 1024 + pix];
    zq_out[zb + (long long)c * 1024 + pix] = zv - r_sh[pix * RQ_RS + c];
  }
}

// ---------------- zq (NCHW f32) -> padded NHWC bf16 [8][34][34][256] ----------------
__global__ __launch_bounds__(256) void to_nhwc_s1(const float* __restrict__ zq,
                                                  unsigned short* __restrict__ o) {
  __shared__ float tsh[32][33];
  int bx = blockIdx.x;
  int ct = bx & 7, y = (bx >> 3) & 31, n = bx >> 8;
  int tid = threadIdx.x;
  int x = tid & 31, cl = tid >> 5;
#pragma unroll
  for (int it = 0; it < 4; ++it) {
    int ci = it * 8 + cl;
    tsh[ci][x] = zq[((long long)(n * 256 + ct * 32 + ci) * 32 + y) * 32 + x];
  }
  __syncthreads();
  int ci = tid & 31, xg = tid >> 5;
#pragma unroll
  for (int it = 0; it < 4; ++it) {
    int xw = it * 8 + xg;
    o[(((long long)n * 34 + y + 1) * 34 + xw + 1) * 256 + ct * 32 + ci] = f2b(tsh[ci][xw]);
  }
}

// ---------------- weight prep: HWIO f32 -> [4ph][CIN/32][4tap][COUT][32] bf16 ----------------
__global__ __launch_bounds__(256) void wprep_k(const float* __restrict__ w,
                                               unsigned short* __restrict__ o,
                                               int CINc, int COUTc) {
  long long total = 16LL * CINc * COUTc;
  long long gid = (long long)blockIdx.x * 256 + threadIdx.x;
  if (gid >= total) return;
  int ci32 = (int)(gid & 31); long long t = gid >> 5;
  int co = (int)(t % COUTc); t /= COUTc;
  int tap = (int)(t & 3); t >>= 2;
  int nch = CINc / 32;
  int ch = (int)(t % nch); int phase = (int)(t / nch);
  int py = phase >> 1, px = phase & 1;
  int ky = py + 2 * (tap >> 1), kx = px + 2 * (tap & 1);
  int ci = ch * 32 + ci32;
  float v = w[(((long long)ky * 4 + kx) * CINc + ci) * COUTc + co];
  o[gid] = f2b(v);
}

// ================= transposed conv k4 s2 MFMA v2: plane-layout LDS ================
template <int CIN, int COUT, int TH, int TW, int Hi, int Wi, bool OUT_NCHW>
__global__ __launch_bounds__(256) void convt2(
    const unsigned short* __restrict__ xin, const unsigned short* __restrict__ wprep,
    const float* __restrict__ bias, unsigned short* __restrict__ outp) {
  constexpr int TWP = TW + 2, ROWS = TH + 2;
  constexpr int Hp = Hi + 2, Wp = Wi + 2;
  constexpr int NCH = CIN / 32;
  constexpr int XUNITS = ROWS * TWP;
  constexpr int XPAD = ((XUNITS + 255) / 256) * 256;
  constexpr int WBASE = 4 * XPAD;
  __shared__ unsigned short lds[(4 * XPAD + 4 * 256) * 8];

  const int tid = threadIdx.x;
  const int wv = tid >> 6, lane = tid & 63;
  const int l15 = lane & 15, seg = lane >> 4;

  constexpr int SW = Wi / TW, SH = Hi / TH;
  const int bx = blockIdx.x;
  const int n = bx / (SH * SW);
  const int srem = bx % (SH * SW);
  const int i0 = (srem / SW) * TH, j0 = (srem % SW) * TW;
  const int cob0 = blockIdx.y * 64;
  const int phase = blockIdx.z;
  const int pyp = phase >> 1, pxp = phase & 1;

  const unsigned short* xsrc = xin + (long long)n * Hp * Wp * CIN;

  f32x4v acc[4][4];
  if (!OUT_NCHW) {
#pragma unroll
    for (int b = 0; b < 4; ++b) {
      float bv = bias[cob0 + b * 16 + l15];
      f32x4v v = {bv, bv, bv, bv};
#pragma unroll
      for (int a = 0; a < 4; ++a) acc[a][b] = v;
    }
  } else {
#pragma unroll
    for (int a = 0; a < 4; ++a) {
      f32x4v v;
#pragma unroll
      for (int q = 0; q < 4; ++q) v[q] = bias[cob0 + a * 16 + seg * 4 + q];
#pragma unroll
      for (int b = 0; b < 4; ++b) acc[a][b] = v;
    }
  }

  for (int ch = 0; ch < NCH; ++ch) {
    __syncthreads();
#pragma unroll
    for (int sg = 0; sg < 4; ++sg) {
#pragma unroll
      for (int it = 0; it < XPAD / 256; ++it) {
        int u = it * 256 + tid;
        int us = u < XUNITS ? u : XUNITS - 1;
        int row = us / TWP, col = us % TWP;
        const unsigned short* g =
            xsrc + ((long long)(i0 + row) * Wp + (j0 + col)) * CIN + ch * 32 + sg * 8;
        gl_lds16(g, (unsigned)(unsigned long long)(const void*)&lds[(sg * XPAD + u) * 8]);
      }
    }
    {
      const unsigned short* wb = wprep + ((long long)phase * NCH + ch) * 4 * COUT * 32;
      int tap = tid >> 6, co = tid & 63;
#pragma unroll
      for (int sg = 0; sg < 4; ++sg) {
        const unsigned short* g = wb + ((long long)tap * COUT + cob0 + co) * 32 + sg * 8;
        gl_lds16(g, (unsigned)(unsigned long long)(const void*)&lds[(WBASE + sg * 256 + tid) * 8]);
      }
    }
    asm volatile("s_waitcnt vmcnt(0)" ::: "memory");
    __syncthreads();
#pragma unroll
    for (int t = 0; t < 4; ++t) {
      int oy = (t >> 1) - 1 + pyp, ox = (t & 1) - 1 + pxp;
      bf16x8v xf[4], wf[4];
#pragma unroll
      for (int i = 0; i < 4; ++i) {
        int p = wv * 64 + i * 16 + l15;
        int r = p / TW, c = p % TW;
        int xrow = r + oy + 1, xcol = c + ox + 1;
        xf[i] = *(const bf16x8v*)&lds[(seg * XPAD + xrow * TWP + xcol) * 8];
        wf[i] = *(const bf16x8v*)&lds[(WBASE + seg * 256 + t * 64 + i * 16 + l15) * 8];
      }
#pragma unroll
      for (int a = 0; a < 4; ++a)
#pragma unroll
        for (int b = 0; b < 4; ++b) {
          if (OUT_NCHW)
            acc[a][b] = __builtin_amdgcn_mfma_f32_16x16x32_bf16(wf[a], xf[b], acc[a][b], 0, 0, 0);
          else
            acc[a][b] = __builtin_amdgcn_mfma_f32_16x16x32_bf16(xf[a], wf[b], acc[a][b], 0, 0, 0);
        }
    }
  }

  if (!OUT_NCHW) {
    constexpr int Wpo = 2 * Wi + 2;
    long long ob_n = (long long)n * (2 * Hi + 2) * Wpo * COUT;
#pragma unroll
    for (int a = 0; a < 4; ++a)
#pragma unroll
      for (int q = 0; q < 4; ++q) {
        int p = wv * 64 + a * 16 + seg * 4 + q;
        int r = p / TW, c = p % TW;
        int yo = 2 * (i0 + r) + pyp + 1, xo = 2 * (j0 + c) + pxp + 1;
        long long ob = ob_n + ((long long)yo * Wpo + xo) * COUT + cob0;
#pragma unroll
        for (int b = 0; b < 4; ++b) {
          float v = fmaxf(acc[a][b][q], 0.f);
          outp[ob + b * 16 + l15] = f2b(v);
        }
      }
  } else {
    constexpr int Ho = 2 * Hi, Wo = 2 * Wi;
#pragma unroll
    for (int a = 0; a < 4; ++a)
#pragma unroll
      for (int q = 0; q < 4; ++q) {
        int co = cob0 + a * 16 + seg * 4 + q;
#pragma unroll
        for (int b = 0; b < 4; ++b) {
          int p = wv * 64 + b * 16 + l15;
          int r = p / TW, c = p % TW;
          int yo = 2 * (i0 + r) + pyp, xo = 2 * (j0 + c) + pxp;
          float v = fmaxf(acc[a][b][q], 0.f);
          outp[((long long)(n * COUT + co) * Ho + yo) * Wo + xo] = f2b(v);
        }
      }
  }
}

// ================= final 3x3 conv v2: LDS-tiled, 32x32 px tile, 3 couts =================
__global__ __launch_bounds__(256) void conv3x3_v2(
    const __hip_bfloat16* __restrict__ in, const float* __restrict__ w,
    const float* __restrict__ bias, float* __restrict__ out) {
  constexpr int H = 256, W = 256, CIN = 128;
  __shared__ float Wsh[3 * CIN * 9];   // 13.8 KB, OIHW linear
  __shared__ float T[4][34][35];       // 19 KB

  const int tid = threadIdx.x;
  for (int u = tid; u < 3 * CIN * 9; u += 256) Wsh[u] = w[u];

  const int bx = blockIdx.x;
  const int n = bx >> 6;
  const int t8 = bx & 63;
  const int y0 = (t8 >> 3) * 32, x0 = (t8 & 7) * 32;
  const int ty = (tid >> 4) * 2;  // 0..30
  const int tx = (tid & 15) * 2;

  float acc[3][2][2];
#pragma unroll
  for (int co = 0; co < 3; ++co) {
    float b = bias[co];
    acc[co][0][0] = b; acc[co][0][1] = b; acc[co][1][0] = b; acc[co][1][1] = b;
  }

  for (int ch = 0; ch < CIN; ch += 4) {
    __syncthreads();
    for (int u = tid; u < 4 * 34 * 34; u += 256) {
      int ci = u / (34 * 34);
      int rem = u % (34 * 34);
      int r = rem / 34, c = rem % 34;
      int yy = y0 + r - 1, xx = x0 + c - 1;
      float v = 0.f;
      if ((unsigned)yy < (unsigned)H && (unsigned)xx < (unsigned)W)
        v = __bfloat162float(in[((long long)(n * CIN + ch + ci) * H + yy) * W + xx]);
      T[ci][r][c] = v;
    }
    __syncthreads();
#pragma unroll
    for (int ci = 0; ci < 4; ++ci) {
      float xv[4][4];
#pragma unroll
      for (int r = 0; r < 4; ++r)
#pragma unroll
        for (int c = 0; c < 4; ++c) xv[r][c] = T[ci][ty + r][tx + c];
#pragma unroll
      for (int co = 0; co < 3; ++co) {
        const float* __restrict__ wp = &Wsh[(co * CIN + ch + ci) * 9];
#pragma unroll
        for (int kh = 0; kh < 3; ++kh)
#pragma unroll
          for (int kw = 0; kw < 3; ++kw) {
            float wt = wp[kh * 3 + kw];
            acc[co][0][0] = fmaf(xv[kh][kw], wt, acc[co][0][0]);
            acc[co][0][1] = fmaf(xv[kh][kw + 1], wt, acc[co][0][1]);
            acc[co][1][0] = fmaf(xv[kh + 1][kw], wt, acc[co][1][0]);
            acc[co][1][1] = fmaf(xv[kh + 1][kw + 1], wt, acc[co][1][1]);
          }
      }
    }
  }
#pragma unroll
  for (int co = 0; co < 3; ++co)
#pragma unroll
    for (int dy = 0; dy < 2; ++dy) {
      long long ob = ((long long)(n * 3 + co) * H + y0 + ty + dy) * W + x0 + tx;
      *reinterpret_cast<float2*>(&out[ob]) = make_float2(acc[co][dy][0], acc[co][dy][1]);
    }
}

// ---------------- fallback helpers + scalar kernels (round-2 path) ----------------
__device__ __forceinline__ float ldf(const float* p, long long i) { return p[i]; }
__device__ __forceinline__ float ldf(const __hip_bfloat16* p, long long i) {
  return __bfloat162float(p[i]);
}
__device__ __forceinline__ void st2(float* p, float a, float b) {
  *reinterpret_cast<float2*>(p) = make_float2(a, b);
}
__device__ __forceinline__ void st2(__hip_bfloat16* p, float a, float b) {
  __hip_bfloat162 v;
  v.x = __float2bfloat16(a); v.y = __float2bfloat16(b);
  *reinterpret_cast<__hip_bfloat162*>(p) = v;
}

__global__ __launch_bounds__(256) void conv3x3_out(
    const __hip_bfloat16* __restrict__ in, const float* __restrict__ w,
    const float* __restrict__ bias, float* __restrict__ out) {
  const int Cin = 128, H = 256, W = 256, Cout = 3;
  long long total = (long long)BATCH * Cout * H * W;
  long long gid = (long long)blockIdx.x * blockDim.x + threadIdx.x;
  if (gid >= total) return;
  int x = (int)(gid % W); long long t = gid / W;
  int y = (int)(t % H); t /= H;
  int co = (int)(t % Cout); int n = (int)(t / Cout);
  float acc = bias[co];
  for (int ci = 0; ci < Cin; ++ci) {
    const __hip_bfloat16* __restrict__ ip = in + ((long long)(n * Cin + ci) * H) * W;
    const float* __restrict__ wp = w + ((long long)(co * Cin + ci)) * 9;
#pragma unroll
    for (int kh = 0; kh < 3; ++kh) {
      int yy = y + kh - 1;
      if ((unsigned)yy >= (unsigned)H) continue;
#pragma unroll
      for (int kw = 0; kw < 3; ++kw) {
        int xx = x + kw - 1;
        if ((unsigned)xx >= (unsigned)W) continue;
        acc = fmaf(__bfloat162float(ip[(long long)yy * W + xx]), wp[kh * 3 + kw], acc);
      }
    }
  }
  out[gid] = acc;
}

__global__ __launch_bounds__(256) void conv4s2_v2(
    const float* __restrict__ in, const float* __restrict__ w,
    const float* __restrict__ bias, float* __restrict__ out,
    int Cin, int Cout, int Hin, int Win, int relu) {
  const int Hout = Hin >> 1, Wout = Win >> 1;
  const int H2 = Hout >> 1, W2 = Wout >> 1;
  const int cogn = Cout >> 2;
  long long total = (long long)BATCH * cogn * H2 * W2;
  long long gid = (long long)blockIdx.x * blockDim.x + threadIdx.x;
  if (gid >= total) return;
  int w2 = (int)(gid % W2); long long t = gid / W2;
  int h2 = (int)(t % H2); t /= H2;
  int cog = (int)(t % cogn); int n = (int)(t / cogn);
  int co0 = cog << 2;
  float a[4][2][2];
#pragma unroll
  for (int j = 0; j < 4; ++j) {
    float b = bias[co0 + j];
    a[j][0][0] = b; a[j][0][1] = b; a[j][1][0] = b; a[j][1][1] = b;
  }
  const int hi0 = 4 * h2 - 1, wi0 = 4 * w2 - 1;
  const long long wstride = (long long)Cin * 16;
  for (int ci = 0; ci < Cin; ++ci) {
    const float* __restrict__ ip = in + ((long long)(n * Cin + ci) * Hin) * Win;
    float xv[6][6];
#pragma unroll
    for (int r = 0; r < 6; ++r) {
      int hi = hi0 + r;
      bool ok = (unsigned)hi < (unsigned)Hin;
#pragma unroll
      for (int c = 0; c < 6; ++c) {
        int wi = wi0 + c;
        xv[r][c] = (ok && (unsigned)wi < (unsigned)Win) ? ip[(long long)hi * Win + wi] : 0.f;
      }
    }
    const float* __restrict__ wp = w + (long long)co0 * wstride + (long long)ci * 16;
#pragma unroll
    for (int kh = 0; kh < 4; ++kh) {
#pragma unroll
      for (int kw = 0; kw < 4; ++kw) {
        int k = (kh << 2) + kw;
        float w0 = wp[k], w1 = wp[wstride + k], w2v = wp[2 * wstride + k], w3 = wp[3 * wstride + k];
#pragma unroll
        for (int dy = 0; dy < 2; ++dy)
#pragma unroll
          for (int dx = 0; dx < 2; ++dx) {
            float v = xv[2 * dy + kh][2 * dx + kw];
            a[0][dy][dx] = fmaf(v, w0, a[0][dy][dx]);
            a[1][dy][dx] = fmaf(v, w1, a[1][dy][dx]);
            a[2][dy][dx] = fmaf(v, w2v, a[2][dy][dx]);
            a[3][dy][dx] = fmaf(v, w3, a[3][dy][dx]);
          }
      }
    }
  }
  long long cs = (long long)Hout * Wout;
  long long ob0 = ((long long)(n * Cout + co0) * Hout + 2 * h2) * Wout + 2 * w2;
#pragma unroll
  for (int j = 0; j < 4; ++j)
#pragma unroll
    for (int dy = 0; dy < 2; ++dy)
#pragma unroll
      for (int dx = 0; dx < 2; ++dx) {
        float v = a[j][dy][dx];
        if (relu) v = fmaxf(v, 0.f);
        out[ob0 + j * cs + (long long)dy * Wout + dx] = v;
      }
}

__global__ __launch_bounds__(256) void conv1x1(
    const float* __restrict__ in, const float* __restrict__ w,
    const float* __restrict__ bias, float* __restrict__ out, int Cin, int Cout) {
  const int HW = 1024;
  const int cogn = Cout >> 2;
  long long total = (long long)BATCH * cogn * HW;
  long long gid = (long long)blockIdx.x * blockDim.x + threadIdx.x;
  if (gid >= total) return;
  int hw = (int)(gid % HW); long long t = gid / HW;
  int cog = (int)(t % cogn); int n = (int)(t / cogn);
  int co0 = cog << 2;
  float a0 = bias[co0], a1 = bias[co0 + 1], a2 = bias[co0 + 2], a3 = bias[co0 + 3];
  for (int ci = 0; ci < Cin; ++ci) {
    float v = in[((long long)(n * Cin + ci)) * HW + hw];
    const float* __restrict__ wp = w + (long long)co0 * Cin + ci;
    a0 = fmaf(v, wp[0], a0);
    a1 = fmaf(v, wp[Cin], a1);
    a2 = fmaf(v, wp[2 * Cin], a2);
    a3 = fmaf(v, wp[3 * Cin], a3);
  }
  long long ob = ((long long)(n * Cout + co0)) * HW + hw;
  out[ob] = a0; out[ob + HW] = a1; out[ob + 2 * HW] = a2; out[ob + 3 * HW] = a3;
}

template <typename TI, typename TO>
__global__ __launch_bounds__(256) void convT4s2_relu(
    const TI* __restrict__ in, const float* __restrict__ w,
    const float* __restrict__ bias, TO* __restrict__ out,
    int Cin, int Cout, int Hi, int Wi) {
  const int Ho = Hi << 1, Wo = Wi << 1;
  long long total = (long long)BATCH * Cout * Hi * Wi;
  long long gid = (long long)blockIdx.x * blockDim.x + threadIdx.x;
  if (gid >= total) return;
  int j = (int)(gid % Wi); long long t = gid / Wi;
  int i = (int)(t % Hi); t /= Hi;
  int co = (int)(t % Cout); int n = (int)(t / Cout);
  const float b = bias[co];
  float a00 = b, a01 = b, a10 = b, a11 = b;
  const long long tapstride = (long long)Cin * Cout;
  const float* __restrict__ wbase = w + co;
  for (int ci = 0; ci < Cin; ++ci) {
    const TI* __restrict__ ip = in + ((long long)(n * Cin + ci) * Hi) * Wi;
    float xv[3][3];
#pragma unroll
    for (int dy = 0; dy < 3; ++dy) {
      int y = i - 1 + dy;
      bool yok = (unsigned)y < (unsigned)Hi;
#pragma unroll
      for (int dx = 0; dx < 3; ++dx) {
        int xx = j - 1 + dx;
        xv[dy][dx] = (yok && (unsigned)xx < (unsigned)Wi) ? ldf(ip, (long long)y * Wi + xx) : 0.f;
      }
    }
    const float* __restrict__ wp = wbase + (long long)ci * Cout;
#define WT(kh, kw) wp[((kh) * 4 + (kw)) * tapstride]
    a00 = fmaf(xv[0][0], WT(0, 0), a00); a00 = fmaf(xv[0][1], WT(0, 2), a00);
    a00 = fmaf(xv[1][0], WT(2, 0), a00); a00 = fmaf(xv[1][1], WT(2, 2), a00);
    a01 = fmaf(xv[0][1], WT(0, 1), a01); a01 = fmaf(xv[0][2], WT(0, 3), a01);
    a01 = fmaf(xv[1][1], WT(2, 1), a01); a01 = fmaf(xv[1][2], WT(2, 3), a01);
    a10 = fmaf(xv[1][0], WT(1, 0), a10); a10 = fmaf(xv[1][1], WT(1, 2), a10);
    a10 = fmaf(xv[2][0], WT(3, 0), a10); a10 = fmaf(xv[2][1], WT(3, 2), a10);
    a11 = fmaf(xv[1][1], WT(1, 1), a11); a11 = fmaf(xv[1][2], WT(1, 3), a11);
    a11 = fmaf(xv[2][1], WT(3, 1), a11); a11 = fmaf(xv[2][2], WT(3, 3), a11);
#undef WT
  }
  a00 = fmaxf(a00, 0.f); a01 = fmaxf(a01, 0.f);
  a10 = fmaxf(a10, 0.f); a11 = fmaxf(a11, 0.f);
  long long ob = ((long long)(n * Cout + co) * Ho + 2 * i) * Wo + 2 * j;
  st2(out + ob, a00, a01);
  st2(out + ob + Wo, a10, a11);
}

extern "C" void kernel_launch(void* const* d_in, const int* in_sizes, int n_in,
                              void* d_out, int out_size, void* d_ws, size_t ws_size,
                              hipStream_t stream) {
  const float* x   = (const float*)d_in[0];
  const float* ew0 = (const float*)d_in[1];  const float* eb0 = (const float*)d_in[2];
  const float* ew1 = (const float*)d_in[3];  const float* eb1 = (const float*)d_in[4];
  const float* ew2 = (const float*)d_in[5];  const float* eb2 = (const float*)d_in[6];
  const float* pw  = (const float*)d_in[7];  const float* pb  = (const float*)d_in[8];
  const float* dw0 = (const float*)d_in[9];  const float* db0 = (const float*)d_in[10];
  const float* dw1 = (const float*)d_in[11]; const float* db1 = (const float*)d_in[12];
  const float* dw2 = (const float*)d_in[13]; const float* db2 = (const float*)d_in[14];
  const float* ow  = (const float*)d_in[15]; const float* ob  = (const float*)d_in[16];
  const float* emb = (const float*)d_in[17];

  float* out   = (float*)d_out;
  float* recon = out;
  float* z     = out + 1572864;
  float* zq    = out + 3670016;
  float* resid = out + 5767168;
  float* codes = out + 14155776;

  char* ws = (char*)d_ws;
  dim3 blk(256);
  auto g = [](long long tot) { return dim3((unsigned)((tot + 255) / 256)); };

  // ---- workspace plan (~204.5 MB) ----
  const size_t OFF_S1IN  = 0ULL;
  const size_t OFF_S1OUT = 4734976ULL;
  const size_t OFF_WP1   = 40419328ULL;
  const size_t OFF_WP2   = 44613632ULL;
  const size_t OFF_E0    = 0ULL;
  const size_t OFF_E1    = 67108864ULL;
  const size_t OFF_E2    = 0ULL;
  const size_t OFF_PWT   = 67108864ULL;
  const size_t OFF_DD2   = 0ULL;
  const size_t OFF_S2OUT = 134217728ULL;
  const size_t OFF_WP3   = 203440128ULL;
  const size_t OFF_EN    = 204488704ULL;
  const size_t WS_NEED   = 204505088ULL;

  if (ws_size >= WS_NEED) {
    float* e0 = (float*)(ws + OFF_E0);
    float* e1 = (float*)(ws + OFF_E1);
    float* e2 = (float*)(ws + OFF_E2);
    float* en = (float*)(ws + OFF_EN);
    float* pwT = (float*)(ws + OFF_PWT);
    unsigned short* s1in  = (unsigned short*)(ws + OFF_S1IN);
    unsigned short* s1out = (unsigned short*)(ws + OFF_S1OUT);
    unsigned short* s2out = (unsigned short*)(ws + OFF_S2OUT);
    unsigned short* dd2   = (unsigned short*)(ws + OFF_DD2);
    unsigned short* wp1   = (unsigned short*)(ws + OFF_WP1);
    unsigned short* wp2   = (unsigned short*)(ws + OFF_WP2);
    unsigned short* wp3   = (unsigned short*)(ws + OFF_WP3);

    emb_norms<<<g(4096), blk, 0, stream>>>(emb, en);

    // encoder
    conv_enc<3, 128, 256, 3, 64><<<dim3(8 * 64, 2), blk, 0, stream>>>(x, ew0, eb0, e0);
    conv_enc<128, 256, 128, 4, 64><<<dim3(8 * 16, 4), blk, 0, stream>>>(e0, ew1, eb1, e1);
    conv_enc<256, 512, 64, 4, 32><<<dim3(8 * 4, 16), blk, 0, stream>>>(e1, ew2, eb2, e2);
    wtrans<<<g(512 * 256), blk, 0, stream>>>(pw, pwT);
    conv1x1_v2<<<dim3(64, 4), blk, 0, stream>>>(e2, pwT, pb, z);

    // residual quantization
    rq_kernel2<<<dim3(256), blk, 0, stream>>>(z, emb, en, zq, resid, codes);

    // decoder prep
    hipMemsetAsync(ws + OFF_S1IN, 0, 4734976ULL, stream);
    hipMemsetAsync(ws + OFF_S1OUT, 0, 35684352ULL, stream);
    hipMemsetAsync(ws + OFF_S2OUT, 0, 69222400ULL, stream);
    to_nhwc_s1<<<dim3(2048), blk, 0, stream>>>(zq, s1in);
    wprep_k<<<g(16LL * 256 * 512), blk, 0, stream>>>(dw0, wp1, 256, 512);
    wprep_k<<<g(16LL * 512 * 256), blk, 0, stream>>>(dw1, wp2, 512, 256);
    wprep_k<<<g(16LL * 256 * 128), blk, 0, stream>>>(dw2, wp3, 256, 128);

    // decoder MFMA stages
    convt2<256, 512, 8, 32, 32, 32, false>
        <<<dim3(32, 8, 4), dim3(256), 0, stream>>>(s1in, wp1, db0, s1out);
    convt2<512, 256, 4, 64, 64, 64, false>
        <<<dim3(128, 4, 4), dim3(256), 0, stream>>>(s1out, wp2, db1, s2out);
    convt2<256, 128, 4, 64, 128, 128, true>
        <<<dim3(512, 2, 4), dim3(256), 0, stream>>>(s2out, wp3, db2, dd2);

    // final 3x3 conv: LDS-tiled
    conv3x3_v2<<<dim3(512), blk, 0, stream>>>((const __hip_bfloat16*)dd2, ow, ob, recon);
  } else {
    // ---- fallback: round-2 layout/path ----
    const size_t OFF_A = 65536ULL;
    const size_t OFF_B = 65536ULL + 67108864ULL;
    float* en = (float*)(ws);
    float* e0 = (float*)(ws + OFF_A);
    float* e1 = (float*)(ws + OFF_B);
    float* e2 = (float*)(ws + OFF_A);
    __hip_bfloat16* dd0 = (__hip_bfloat16*)(ws + OFF_B);
    __hip_bfloat16* dd1 = (__hip_bfloat16*)(ws + OFF_A);
    __hip_bfloat16* dd2 = (__hip_bfloat16*)(ws + OFF_B);

    emb_norms<<<g(4096), blk, 0, stream>>>(emb, en);
    conv4s2_v2<<<g(8LL * 32 * 64 * 64), blk, 0, stream>>>(x, ew0, eb0, e0, 3, 128, 256, 256, 1);
    conv4s2_v2<<<g(8LL * 64 * 32 * 32), blk, 0, stream>>>(e0, ew1, eb1, e1, 128, 256, 128, 128, 1);
    conv4s2_v2<<<g(8LL * 128 * 16 * 16), blk, 0, stream>>>(e1, ew2, eb2, e2, 256, 512, 64, 64, 1);
    conv1x1<<<g(8LL * 64 * 1024), blk, 0, stream>>>(e2, pw, pb, z, 512, 256);
    rq_kernel2<<<dim3(256), blk, 0, stream>>>(z, emb, en, zq, resid, codes);
    convT4s2_relu<float, __hip_bfloat16>
        <<<g(8LL * 512 * 32 * 32), blk, 0, stream>>>(zq, dw0, db0, dd0, 256, 512, 32, 32);
    convT4s2_relu<__hip_bfloat16, __hip_bfloat16>
        <<<g(8LL * 256 * 64 * 64), blk, 0, stream>>>(dd0, dw1, db1, dd1, 512, 256, 64, 64);
    convT4s2_relu<__hip_bfloat16, __hip_bfloat16>
        <<<g(8LL * 128 * 128 * 128), blk, 0, stream>>>(dd1, dw2, db2, dd2, 256, 128, 128, 128);
    conv3x3_out<<<g(8LL * 3 * 256 * 256), blk, 0, stream>>>(dd2, ow, ob, recon);
  }
}